// Round 1
// baseline (5965.731 us; speedup 1.0000x reference)
//
#include <hip/hip_runtime.h>
#include <hip/hip_bf16.h>

#define N_NODES 100000
#define N_EDGES 1600000
#define IN_F    32
#define D       128
#define OUT_F   16

// ---------------------------------------------------------------------------
// h0 = x @ W_emb + b_emb      [N,32] @ [32,128] -> [N,128]
// block: 256 threads = 2 nodes x 128 cols
// ---------------------------------------------------------------------------
__global__ __launch_bounds__(256) void k_embed(const float* __restrict__ x,
                                               const float* __restrict__ W,
                                               const float* __restrict__ b,
                                               float* __restrict__ h) {
    __shared__ float xs[2][IN_F];
    const int col = threadIdx.x & 127;
    const int ng  = threadIdx.x >> 7;          // node within block (0,1)
    const int node = blockIdx.x * 2 + ng;

    // cooperative load of 2 x-rows (64 floats)
    if (threadIdx.x < 64) {
        int r = threadIdx.x >> 5, c = threadIdx.x & 31;
        int n2 = blockIdx.x * 2 + r;
        xs[r][c] = (n2 < N_NODES) ? x[(long)n2 * IN_F + c] : 0.f;
    }
    __syncthreads();
    if (node >= N_NODES) return;

    float acc = b[col];
#pragma unroll
    for (int k = 0; k < IN_F; ++k)
        acc += xs[ng][k] * W[k * D + col];
    h[(long)node * D + col] = acc;
}

// ---------------------------------------------------------------------------
// in-degree counts
// ---------------------------------------------------------------------------
__global__ __launch_bounds__(256) void k_count(const int* __restrict__ dst,
                                               int* __restrict__ cnt) {
    int e = blockIdx.x * 256 + threadIdx.x;
    if (e < N_EDGES) atomicAdd(&cnt[dst[e]], 1);
}

// ---------------------------------------------------------------------------
// scatter-add: agg[dst] += h[src]   (32 threads / edge, float4 per thread)
// ---------------------------------------------------------------------------
__global__ __launch_bounds__(256) void k_scatter(const float* __restrict__ h,
                                                 const int* __restrict__ src,
                                                 const int* __restrict__ dst,
                                                 float* __restrict__ agg) {
    long tid = (long)blockIdx.x * 256 + threadIdx.x;
    int e = (int)(tid >> 5);            // 32 threads per edge
    if (e >= N_EDGES) return;
    int q = ((int)tid & 31) << 2;       // float4 slot (0,4,...,124)

    int s = src[e];
    int d = dst[e];
    const float4 v = *reinterpret_cast<const float4*>(h + (long)s * D + q);
    float* a = agg + (long)d * D + q;
    atomicAdd(a + 0, v.x);
    atomicAdd(a + 1, v.y);
    atomicAdd(a + 2, v.z);
    atomicAdd(a + 3, v.w);
}

// ---------------------------------------------------------------------------
// hout = relu( (agg/max(cnt,1)) @ Wrel + hin @ Wroot + b )
// block: 256 threads, tile of 32 nodes x 128 cols
// thread (col = t&127, ng = t>>7) computes 16 node-outputs for its column
// ---------------------------------------------------------------------------
__global__ __launch_bounds__(256) void k_transform(const float* __restrict__ agg,
                                                   const int* __restrict__ cnt,
                                                   const float* __restrict__ hin,
                                                   const float* __restrict__ Wrel,
                                                   const float* __restrict__ Wroot,
                                                   const float* __restrict__ b,
                                                   float* __restrict__ hout,
                                                   int nNodes) {
    __shared__ float aT[32][D];
    __shared__ float hT[32][D];
    const int base = blockIdx.x * 32;

    // cooperative tile load: 32 rows x 32 float4 per tile
    for (int i = threadIdx.x; i < 32 * 32; i += 256) {
        int r = i >> 5;
        int c4 = (i & 31) << 2;
        int n = base + r;
        float4 av, hv;
        if (n < nNodes) {
            av = *reinterpret_cast<const float4*>(agg + (long)n * D + c4);
            hv = *reinterpret_cast<const float4*>(hin + (long)n * D + c4);
            float sc = 1.f / fmaxf((float)cnt[n], 1.f);
            av.x *= sc; av.y *= sc; av.z *= sc; av.w *= sc;
        } else {
            av = make_float4(0.f, 0.f, 0.f, 0.f);
            hv = make_float4(0.f, 0.f, 0.f, 0.f);
        }
        *reinterpret_cast<float4*>(&aT[r][c4]) = av;
        *reinterpret_cast<float4*>(&hT[r][c4]) = hv;
    }
    __syncthreads();

    const int col = threadIdx.x & 127;
    const int ng  = threadIdx.x >> 7;          // node group 0/1 -> rows ng*16..+15

    float acc[16];
#pragma unroll
    for (int n = 0; n < 16; ++n) acc[n] = 0.f;

    for (int kc = 0; kc < D; kc += 8) {
        float wr[8], wo[8];
#pragma unroll
        for (int j = 0; j < 8; ++j) {
            wr[j] = Wrel[(kc + j) * D + col];
            wo[j] = Wroot[(kc + j) * D + col];
        }
#pragma unroll
        for (int n = 0; n < 16; ++n) {
            int row = ng * 16 + n;
            float4 a0 = *reinterpret_cast<const float4*>(&aT[row][kc]);
            float4 a1 = *reinterpret_cast<const float4*>(&aT[row][kc + 4]);
            float4 h0 = *reinterpret_cast<const float4*>(&hT[row][kc]);
            float4 h1 = *reinterpret_cast<const float4*>(&hT[row][kc + 4]);
            acc[n] += a0.x * wr[0] + a0.y * wr[1] + a0.z * wr[2] + a0.w * wr[3]
                    + a1.x * wr[4] + a1.y * wr[5] + a1.z * wr[6] + a1.w * wr[7]
                    + h0.x * wo[0] + h0.y * wo[1] + h0.z * wo[2] + h0.w * wo[3]
                    + h1.x * wo[4] + h1.y * wo[5] + h1.z * wo[6] + h1.w * wo[7];
        }
    }

    const float bias = b[col];
#pragma unroll
    for (int n = 0; n < 16; ++n) {
        int node = base + ng * 16 + n;
        if (node < nNodes)
            hout[(long)node * D + col] = fmaxf(acc[n] + bias, 0.f);
    }
}

// ---------------------------------------------------------------------------
// out = h @ W_out + b_out     [N,128] @ [128,16] -> [N,16]
// one thread per output element
// ---------------------------------------------------------------------------
__global__ __launch_bounds__(256) void k_out(const float* __restrict__ h,
                                             const float* __restrict__ W,
                                             const float* __restrict__ b,
                                             float* __restrict__ out) {
    long t = (long)blockIdx.x * 256 + threadIdx.x;
    if (t >= (long)N_NODES * OUT_F) return;
    int n = (int)(t >> 4);
    int o = (int)t & 15;
    const float* hr = h + (long)n * D;
    float acc = b[o];
#pragma unroll
    for (int k = 0; k < D; k += 4) {
        float4 hv = *reinterpret_cast<const float4*>(hr + k);
        acc += hv.x * W[(k + 0) * OUT_F + o]
             + hv.y * W[(k + 1) * OUT_F + o]
             + hv.z * W[(k + 2) * OUT_F + o]
             + hv.w * W[(k + 3) * OUT_F + o];
    }
    out[t] = acc;
}

// ---------------------------------------------------------------------------
extern "C" void kernel_launch(void* const* d_in, const int* in_sizes, int n_in,
                              void* d_out, int out_size, void* d_ws, size_t ws_size,
                              hipStream_t stream) {
    const float* x      = (const float*)d_in[0];
    const int*   edge   = (const int*)d_in[1];   // [2, E] row-major: src then dst
    const float* W_emb  = (const float*)d_in[2];
    const float* b_emb  = (const float*)d_in[3];
    const float* W1_rel = (const float*)d_in[4];
    const float* W1_root= (const float*)d_in[5];
    const float* b1     = (const float*)d_in[6];
    const float* W2_rel = (const float*)d_in[7];
    const float* W2_root= (const float*)d_in[8];
    const float* b2     = (const float*)d_in[9];
    const float* W_out  = (const float*)d_in[10];
    const float* b_out  = (const float*)d_in[11];
    float* out = (float*)d_out;

    const int* src = edge;
    const int* dst = edge + N_EDGES;

    // workspace layout
    float* hA  = (float*)d_ws;                       // N*D
    float* hB  = hA + (size_t)N_NODES * D;           // N*D
    float* agg = hB + (size_t)N_NODES * D;           // N*D
    int*   cnt = (int*)(agg + (size_t)N_NODES * D);  // N

    const int scatterBlocks = (int)(((long)N_EDGES * 32 + 255) / 256);

    // degree counts (shared by both conv layers)
    hipMemsetAsync(cnt, 0, N_NODES * sizeof(int), stream);
    k_count<<<(N_EDGES + 255) / 256, 256, 0, stream>>>(dst, cnt);

    // node embed
    k_embed<<<(N_NODES + 1) / 2, 256, 0, stream>>>(x, W_emb, b_emb, hA);

    // conv1
    hipMemsetAsync(agg, 0, (size_t)N_NODES * D * sizeof(float), stream);
    k_scatter<<<scatterBlocks, 256, 0, stream>>>(hA, src, dst, agg);
    k_transform<<<(N_NODES + 31) / 32, 256, 0, stream>>>(agg, cnt, hA,
                                                         W1_rel, W1_root, b1, hB, N_NODES);

    // conv2
    hipMemsetAsync(agg, 0, (size_t)N_NODES * D * sizeof(float), stream);
    k_scatter<<<scatterBlocks, 256, 0, stream>>>(hB, src, dst, agg);
    k_transform<<<(N_NODES + 31) / 32, 256, 0, stream>>>(agg, cnt, hB,
                                                         W2_rel, W2_root, b2, hA, N_NODES);

    // final projection
    k_out<<<((long)N_NODES * OUT_F + 255) / 256, 256, 0, stream>>>(hA, W_out, b_out, out);
}

// Round 2
// 907.094 us; speedup vs baseline: 6.5768x; 6.5768x over previous
//
#include <hip/hip_runtime.h>
#include <hip/hip_bf16.h>

#define N_NODES 100000
#define N_EDGES 1600000
#define IN_F    32
#define D       128
#define OUT_F   16
#define NB      ((N_NODES + 255) / 256)   // 391 scan blocks

// ---------------------------------------------------------------------------
// h0 = x @ W_emb + b_emb      [N,32] @ [32,128] -> [N,128]
// ---------------------------------------------------------------------------
__global__ __launch_bounds__(256) void k_embed(const float* __restrict__ x,
                                               const float* __restrict__ W,
                                               const float* __restrict__ b,
                                               float* __restrict__ h) {
    __shared__ float xs[2][IN_F];
    const int col = threadIdx.x & 127;
    const int ng  = threadIdx.x >> 7;
    const int node = blockIdx.x * 2 + ng;

    if (threadIdx.x < 64) {
        int r = threadIdx.x >> 5, c = threadIdx.x & 31;
        int n2 = blockIdx.x * 2 + r;
        xs[r][c] = (n2 < N_NODES) ? x[(long)n2 * IN_F + c] : 0.f;
    }
    __syncthreads();
    if (node >= N_NODES) return;

    float acc = b[col];
#pragma unroll
    for (int k = 0; k < IN_F; ++k)
        acc += xs[ng][k] * W[k * D + col];
    h[(long)node * D + col] = acc;
}

// ---------------------------------------------------------------------------
// in-degree counts (int atomics into 400 KB L2-resident array — cheap)
// ---------------------------------------------------------------------------
__global__ __launch_bounds__(256) void k_count(const int* __restrict__ dst,
                                               int* __restrict__ cnt) {
    int e = blockIdx.x * 256 + threadIdx.x;
    if (e < N_EDGES) atomicAdd(&cnt[dst[e]], 1);
}

// ---------------------------------------------------------------------------
// 3-kernel exclusive prefix scan of cnt[N_NODES] -> offsets (+ cursor copy)
// ---------------------------------------------------------------------------
__global__ __launch_bounds__(256) void k_scan1(const int* __restrict__ cnt,
                                               int* __restrict__ part,
                                               int* __restrict__ blockSums) {
    __shared__ int s[256];
    int i = blockIdx.x * 256 + threadIdx.x;
    int v = (i < N_NODES) ? cnt[i] : 0;
    s[threadIdx.x] = v;
    __syncthreads();
    for (int off = 1; off < 256; off <<= 1) {
        int x = (threadIdx.x >= off) ? s[threadIdx.x - off] : 0;
        __syncthreads();
        s[threadIdx.x] += x;
        __syncthreads();
    }
    if (i < N_NODES) part[i] = s[threadIdx.x] - v;     // exclusive within block
    if (threadIdx.x == 255) blockSums[blockIdx.x] = s[255];
}

__global__ __launch_bounds__(512) void k_scan2(int* __restrict__ blockSums) {
    __shared__ int s[512];
    int t = threadIdx.x;
    int v = (t < NB) ? blockSums[t] : 0;
    s[t] = v;
    __syncthreads();
    for (int off = 1; off < 512; off <<= 1) {
        int x = (t >= off) ? s[t - off] : 0;
        __syncthreads();
        s[t] += x;
        __syncthreads();
    }
    if (t < NB) blockSums[t] = s[t] - v;               // exclusive block offsets
}

__global__ __launch_bounds__(256) void k_scan3(int* __restrict__ offsets,   // in: part, out: final
                                               const int* __restrict__ blockSums,
                                               int* __restrict__ cursor) {
    int i = blockIdx.x * 256 + threadIdx.x;
    if (i < N_NODES) {
        int o = offsets[i] + blockSums[blockIdx.x];
        offsets[i] = o;
        cursor[i]  = o;
    }
}

// ---------------------------------------------------------------------------
// fill CSR adjacency: csr[cursor[dst]++] = src   (int atomics only)
// ---------------------------------------------------------------------------
__global__ __launch_bounds__(256) void k_fill(const int* __restrict__ src,
                                              const int* __restrict__ dst,
                                              int* __restrict__ cursor,
                                              int* __restrict__ csr) {
    int e = blockIdx.x * 256 + threadIdx.x;
    if (e < N_EDGES) {
        int p = atomicAdd(&cursor[dst[e]], 1);
        csr[p] = src[e];
    }
}

// ---------------------------------------------------------------------------
// agg[n] = mean_{s in csr[n]} h[s]   — deterministic gather, no f32 atomics
// block: 256 threads = 8 nodes x 32 lanes, float4 per lane
// ---------------------------------------------------------------------------
__global__ __launch_bounds__(256) void k_gather(const float* __restrict__ h,
                                                const int* __restrict__ csr,
                                                const int* __restrict__ offsets,
                                                const int* __restrict__ cnt,
                                                float* __restrict__ agg) {
    const int node = blockIdx.x * 8 + (threadIdx.x >> 5);
    const int q = (threadIdx.x & 31) << 2;
    if (node >= N_NODES) return;

    const int beg = offsets[node];
    const int deg = cnt[node];
    const int end = beg + deg;

    float4 acc = make_float4(0.f, 0.f, 0.f, 0.f);
    int i = beg;
    for (; i + 1 < end; i += 2) {                 // 2x unroll for MLP latency
        int s0 = csr[i], s1 = csr[i + 1];
        const float4 v0 = *reinterpret_cast<const float4*>(h + (long)s0 * D + q);
        const float4 v1 = *reinterpret_cast<const float4*>(h + (long)s1 * D + q);
        acc.x += v0.x + v1.x;
        acc.y += v0.y + v1.y;
        acc.z += v0.z + v1.z;
        acc.w += v0.w + v1.w;
    }
    if (i < end) {
        int s0 = csr[i];
        const float4 v0 = *reinterpret_cast<const float4*>(h + (long)s0 * D + q);
        acc.x += v0.x; acc.y += v0.y; acc.z += v0.z; acc.w += v0.w;
    }

    const float sc = 1.f / fmaxf((float)deg, 1.f);
    acc.x *= sc; acc.y *= sc; acc.z *= sc; acc.w *= sc;
    *reinterpret_cast<float4*>(agg + (long)node * D + q) = acc;
}

// ---------------------------------------------------------------------------
// hout = relu( agg @ Wrel + hin @ Wroot + b )    (agg already mean-scaled)
// ---------------------------------------------------------------------------
__global__ __launch_bounds__(256) void k_transform(const float* __restrict__ agg,
                                                   const float* __restrict__ hin,
                                                   const float* __restrict__ Wrel,
                                                   const float* __restrict__ Wroot,
                                                   const float* __restrict__ b,
                                                   float* __restrict__ hout,
                                                   int nNodes) {
    __shared__ float aT[32][D];
    __shared__ float hT[32][D];
    const int base = blockIdx.x * 32;

    for (int i = threadIdx.x; i < 32 * 32; i += 256) {
        int r = i >> 5;
        int c4 = (i & 31) << 2;
        int n = base + r;
        float4 av, hv;
        if (n < nNodes) {
            av = *reinterpret_cast<const float4*>(agg + (long)n * D + c4);
            hv = *reinterpret_cast<const float4*>(hin + (long)n * D + c4);
        } else {
            av = make_float4(0.f, 0.f, 0.f, 0.f);
            hv = make_float4(0.f, 0.f, 0.f, 0.f);
        }
        *reinterpret_cast<float4*>(&aT[r][c4]) = av;
        *reinterpret_cast<float4*>(&hT[r][c4]) = hv;
    }
    __syncthreads();

    const int col = threadIdx.x & 127;
    const int ng  = threadIdx.x >> 7;

    float acc[16];
#pragma unroll
    for (int n = 0; n < 16; ++n) acc[n] = 0.f;

    for (int kc = 0; kc < D; kc += 8) {
        float wr[8], wo[8];
#pragma unroll
        for (int j = 0; j < 8; ++j) {
            wr[j] = Wrel[(kc + j) * D + col];
            wo[j] = Wroot[(kc + j) * D + col];
        }
#pragma unroll
        for (int n = 0; n < 16; ++n) {
            int row = ng * 16 + n;
            float4 a0 = *reinterpret_cast<const float4*>(&aT[row][kc]);
            float4 a1 = *reinterpret_cast<const float4*>(&aT[row][kc + 4]);
            float4 h0 = *reinterpret_cast<const float4*>(&hT[row][kc]);
            float4 h1 = *reinterpret_cast<const float4*>(&hT[row][kc + 4]);
            acc[n] += a0.x * wr[0] + a0.y * wr[1] + a0.z * wr[2] + a0.w * wr[3]
                    + a1.x * wr[4] + a1.y * wr[5] + a1.z * wr[6] + a1.w * wr[7]
                    + h0.x * wo[0] + h0.y * wo[1] + h0.z * wo[2] + h0.w * wo[3]
                    + h1.x * wo[4] + h1.y * wo[5] + h1.z * wo[6] + h1.w * wo[7];
        }
    }

    const float bias = b[col];
#pragma unroll
    for (int n = 0; n < 16; ++n) {
        int node = base + ng * 16 + n;
        if (node < nNodes)
            hout[(long)node * D + col] = fmaxf(acc[n] + bias, 0.f);
    }
}

// ---------------------------------------------------------------------------
// out = h @ W_out + b_out     [N,128] @ [128,16] -> [N,16]
// ---------------------------------------------------------------------------
__global__ __launch_bounds__(256) void k_out(const float* __restrict__ h,
                                             const float* __restrict__ W,
                                             const float* __restrict__ b,
                                             float* __restrict__ out) {
    long t = (long)blockIdx.x * 256 + threadIdx.x;
    if (t >= (long)N_NODES * OUT_F) return;
    int n = (int)(t >> 4);
    int o = (int)t & 15;
    const float* hr = h + (long)n * D;
    float acc = b[o];
#pragma unroll
    for (int k = 0; k < D; k += 4) {
        float4 hv = *reinterpret_cast<const float4*>(hr + k);
        acc += hv.x * W[(k + 0) * OUT_F + o]
             + hv.y * W[(k + 1) * OUT_F + o]
             + hv.z * W[(k + 2) * OUT_F + o]
             + hv.w * W[(k + 3) * OUT_F + o];
    }
    out[t] = acc;
}

// ---------------------------------------------------------------------------
extern "C" void kernel_launch(void* const* d_in, const int* in_sizes, int n_in,
                              void* d_out, int out_size, void* d_ws, size_t ws_size,
                              hipStream_t stream) {
    const float* x      = (const float*)d_in[0];
    const int*   edge   = (const int*)d_in[1];
    const float* W_emb  = (const float*)d_in[2];
    const float* b_emb  = (const float*)d_in[3];
    const float* W1_rel = (const float*)d_in[4];
    const float* W1_root= (const float*)d_in[5];
    const float* b1     = (const float*)d_in[6];
    const float* W2_rel = (const float*)d_in[7];
    const float* W2_root= (const float*)d_in[8];
    const float* b2     = (const float*)d_in[9];
    const float* W_out  = (const float*)d_in[10];
    const float* b_out  = (const float*)d_in[11];
    float* out = (float*)d_out;

    const int* src = edge;
    const int* dst = edge + N_EDGES;

    // workspace layout (all 16B-aligned by construction)
    float* hA      = (float*)d_ws;                        // N*D
    float* hB      = hA + (size_t)N_NODES * D;            // N*D
    float* agg     = hB + (size_t)N_NODES * D;            // N*D
    int*   cnt     = (int*)(agg + (size_t)N_NODES * D);   // N
    int*   offsets = cnt + N_NODES;                       // N (doubles as scan partial)
    int*   cursor  = offsets + N_NODES;                   // N
    int*   bsums   = cursor + N_NODES;                    // NB
    int*   csr     = bsums + ((NB + 3) & ~3);             // E

    // ---- CSR build (int atomics only) ----
    hipMemsetAsync(cnt, 0, N_NODES * sizeof(int), stream);
    k_count<<<(N_EDGES + 255) / 256, 256, 0, stream>>>(dst, cnt);
    k_scan1<<<NB, 256, 0, stream>>>(cnt, offsets, bsums);
    k_scan2<<<1, 512, 0, stream>>>(bsums);
    k_scan3<<<NB, 256, 0, stream>>>(offsets, bsums, cursor);
    k_fill<<<(N_EDGES + 255) / 256, 256, 0, stream>>>(src, dst, cursor, csr);

    // ---- node embed ----
    k_embed<<<(N_NODES + 1) / 2, 256, 0, stream>>>(x, W_emb, b_emb, hA);

    // ---- conv1 ----
    k_gather<<<(N_NODES + 7) / 8, 256, 0, stream>>>(hA, csr, offsets, cnt, agg);
    k_transform<<<(N_NODES + 31) / 32, 256, 0, stream>>>(agg, hA, W1_rel, W1_root, b1, hB, N_NODES);

    // ---- conv2 ----
    k_gather<<<(N_NODES + 7) / 8, 256, 0, stream>>>(hB, csr, offsets, cnt, agg);
    k_transform<<<(N_NODES + 31) / 32, 256, 0, stream>>>(agg, hB, W2_rel, W2_root, b2, hA, N_NODES);

    // ---- final projection ----
    k_out<<<((long)N_NODES * OUT_F + 255) / 256, 256, 0, stream>>>(hA, W_out, b_out, out);
}

// Round 3
// 870.770 us; speedup vs baseline: 6.8511x; 1.0417x over previous
//
#include <hip/hip_runtime.h>
#include <hip/hip_bf16.h>

#define N_NODES 100000
#define N_EDGES 1600000
#define IN_F    32
#define D       128
#define OUT_F   16
#define NB      ((N_NODES + 255) / 256)   // 391 scan blocks

// ---------------------------------------------------------------------------
// h0 = x @ W_emb + b_emb      [N,32] @ [32,128] -> [N,128]
// ---------------------------------------------------------------------------
__global__ __launch_bounds__(256) void k_embed(const float* __restrict__ x,
                                               const float* __restrict__ W,
                                               const float* __restrict__ b,
                                               float* __restrict__ h) {
    __shared__ float xs[2][IN_F];
    const int col = threadIdx.x & 127;
    const int ng  = threadIdx.x >> 7;
    const int node = blockIdx.x * 2 + ng;

    if (threadIdx.x < 64) {
        int r = threadIdx.x >> 5, c = threadIdx.x & 31;
        int n2 = blockIdx.x * 2 + r;
        xs[r][c] = (n2 < N_NODES) ? x[(long)n2 * IN_F + c] : 0.f;
    }
    __syncthreads();
    if (node >= N_NODES) return;

    float acc = b[col];
#pragma unroll
    for (int k = 0; k < IN_F; ++k)
        acc += xs[ng][k] * W[k * D + col];
    h[(long)node * D + col] = acc;
}

// ---------------------------------------------------------------------------
// in-degree counts (int atomics into 400 KB L2-resident array)
// ---------------------------------------------------------------------------
__global__ __launch_bounds__(256) void k_count(const int* __restrict__ dst,
                                               int* __restrict__ cnt) {
    int e = blockIdx.x * 256 + threadIdx.x;
    if (e < N_EDGES) atomicAdd(&cnt[dst[e]], 1);
}

// ---------------------------------------------------------------------------
// 3-kernel exclusive prefix scan of cnt[N_NODES] -> offsets (+ cursor copy)
// ---------------------------------------------------------------------------
__global__ __launch_bounds__(256) void k_scan1(const int* __restrict__ cnt,
                                               int* __restrict__ part,
                                               int* __restrict__ blockSums) {
    __shared__ int s[256];
    int i = blockIdx.x * 256 + threadIdx.x;
    int v = (i < N_NODES) ? cnt[i] : 0;
    s[threadIdx.x] = v;
    __syncthreads();
    for (int off = 1; off < 256; off <<= 1) {
        int x = (threadIdx.x >= off) ? s[threadIdx.x - off] : 0;
        __syncthreads();
        s[threadIdx.x] += x;
        __syncthreads();
    }
    if (i < N_NODES) part[i] = s[threadIdx.x] - v;
    if (threadIdx.x == 255) blockSums[blockIdx.x] = s[255];
}

__global__ __launch_bounds__(512) void k_scan2(int* __restrict__ blockSums) {
    __shared__ int s[512];
    int t = threadIdx.x;
    int v = (t < NB) ? blockSums[t] : 0;
    s[t] = v;
    __syncthreads();
    for (int off = 1; off < 512; off <<= 1) {
        int x = (t >= off) ? s[t - off] : 0;
        __syncthreads();
        s[t] += x;
        __syncthreads();
    }
    if (t < NB) blockSums[t] = s[t] - v;
}

__global__ __launch_bounds__(256) void k_scan3(int* __restrict__ offsets,
                                               const int* __restrict__ blockSums,
                                               int* __restrict__ cursor) {
    int i = blockIdx.x * 256 + threadIdx.x;
    if (i < N_NODES) {
        int o = offsets[i] + blockSums[blockIdx.x];
        offsets[i] = o;
        cursor[i]  = o;
    }
}

// ---------------------------------------------------------------------------
// fill CSR adjacency: csr[cursor[dst]++] = src
// ---------------------------------------------------------------------------
__global__ __launch_bounds__(256) void k_fill(const int* __restrict__ src,
                                              const int* __restrict__ dst,
                                              int* __restrict__ cursor,
                                              int* __restrict__ csr) {
    int e = blockIdx.x * 256 + threadIdx.x;
    if (e < N_EDGES) {
        int p = atomicAdd(&cursor[dst[e]], 1);
        csr[p] = src[e];
    }
}

// ---------------------------------------------------------------------------
// agg[n] = mean_{s in csr[n]} h[s]   — deterministic gather
// block: 256 threads = 8 nodes x 32 lanes, float4 per lane; 4x unrolled MLP
// ---------------------------------------------------------------------------
__global__ __launch_bounds__(256) void k_gather(const float* __restrict__ h,
                                                const int* __restrict__ csr,
                                                const int* __restrict__ offsets,
                                                const int* __restrict__ cnt,
                                                float* __restrict__ agg) {
    const int node = blockIdx.x * 8 + (threadIdx.x >> 5);
    const int q = (threadIdx.x & 31) << 2;
    if (node >= N_NODES) return;

    const int beg = offsets[node];
    const int deg = cnt[node];
    const int end = beg + deg;

    float4 acc0 = make_float4(0.f, 0.f, 0.f, 0.f);
    float4 acc1 = make_float4(0.f, 0.f, 0.f, 0.f);
    int i = beg;
    for (; i + 3 < end; i += 4) {
        int s0 = csr[i], s1 = csr[i + 1], s2 = csr[i + 2], s3 = csr[i + 3];
        const float4 v0 = *reinterpret_cast<const float4*>(h + (long)s0 * D + q);
        const float4 v1 = *reinterpret_cast<const float4*>(h + (long)s1 * D + q);
        const float4 v2 = *reinterpret_cast<const float4*>(h + (long)s2 * D + q);
        const float4 v3 = *reinterpret_cast<const float4*>(h + (long)s3 * D + q);
        acc0.x += v0.x + v1.x;  acc1.x += v2.x + v3.x;
        acc0.y += v0.y + v1.y;  acc1.y += v2.y + v3.y;
        acc0.z += v0.z + v1.z;  acc1.z += v2.z + v3.z;
        acc0.w += v0.w + v1.w;  acc1.w += v2.w + v3.w;
    }
    for (; i < end; ++i) {
        int s0 = csr[i];
        const float4 v0 = *reinterpret_cast<const float4*>(h + (long)s0 * D + q);
        acc0.x += v0.x; acc0.y += v0.y; acc0.z += v0.z; acc0.w += v0.w;
    }
    acc0.x += acc1.x; acc0.y += acc1.y; acc0.z += acc1.z; acc0.w += acc1.w;

    const float sc = 1.f / fmaxf((float)deg, 1.f);
    acc0.x *= sc; acc0.y *= sc; acc0.z *= sc; acc0.w *= sc;
    *reinterpret_cast<float4*>(agg + (long)node * D + q) = acc0;
}

// ---------------------------------------------------------------------------
// hout = relu( agg @ Wrel + hin @ Wroot + b )    (agg already mean-scaled)
// 32-node x 128-col tile, 256 threads, per-thread 4 nodes x 4 cols.
// A-side from LDS (broadcast, conflict-free), B-side (weights) from global/L2.
// 100000 % 32 == 0 -> no tail handling.
// ---------------------------------------------------------------------------
__global__ __launch_bounds__(256) void k_transform(const float* __restrict__ agg,
                                                   const float* __restrict__ hin,
                                                   const float* __restrict__ Wrel,
                                                   const float* __restrict__ Wroot,
                                                   const float* __restrict__ b,
                                                   float* __restrict__ hout) {
    __shared__ float aT[32][D];
    __shared__ float hT[32][D];
    const int base = blockIdx.x * 32;

    // stage 32 rows of agg and hin (coalesced float4)
    for (int i = threadIdx.x; i < 32 * 32; i += 256) {
        int r = i >> 5;
        int c4 = (i & 31) << 2;
        long n = base + r;
        *reinterpret_cast<float4*>(&aT[r][c4]) =
            *reinterpret_cast<const float4*>(agg + n * D + c4);
        *reinterpret_cast<float4*>(&hT[r][c4]) =
            *reinterpret_cast<const float4*>(hin + n * D + c4);
    }
    __syncthreads();

    const int tc  = threadIdx.x & 31;   // col group -> cols 4tc..4tc+3
    const int tr4 = (threadIdx.x >> 5) << 2;  // first of 4 node rows
    const int col = tc << 2;

    float acc[4][4];
#pragma unroll
    for (int i = 0; i < 4; ++i)
#pragma unroll
        for (int j = 0; j < 4; ++j) acc[i][j] = 0.f;

#define GEMM_LOOP(AT, W)                                                        \
    _Pragma("unroll 2")                                                         \
    for (int k = 0; k < D; k += 4) {                                            \
        float4 w0 = *reinterpret_cast<const float4*>(W + (k + 0) * D + col);    \
        float4 w1 = *reinterpret_cast<const float4*>(W + (k + 1) * D + col);    \
        float4 w2 = *reinterpret_cast<const float4*>(W + (k + 2) * D + col);    \
        float4 w3 = *reinterpret_cast<const float4*>(W + (k + 3) * D + col);    \
        _Pragma("unroll")                                                       \
        for (int i = 0; i < 4; ++i) {                                           \
            float4 a = *reinterpret_cast<const float4*>(&AT[tr4 + i][k]);       \
            acc[i][0] += a.x * w0.x + a.y * w1.x + a.z * w2.x + a.w * w3.x;     \
            acc[i][1] += a.x * w0.y + a.y * w1.y + a.z * w2.y + a.w * w3.y;     \
            acc[i][2] += a.x * w0.z + a.y * w1.z + a.z * w2.z + a.w * w3.z;     \
            acc[i][3] += a.x * w0.w + a.y * w1.w + a.z * w2.w + a.w * w3.w;     \
        }                                                                       \
    }

    GEMM_LOOP(aT, Wrel)
    GEMM_LOOP(hT, Wroot)
#undef GEMM_LOOP

    const float4 bias = *reinterpret_cast<const float4*>(b + col);
#pragma unroll
    for (int i = 0; i < 4; ++i) {
        long node = base + tr4 + i;
        float4 o;
        o.x = fmaxf(acc[i][0] + bias.x, 0.f);
        o.y = fmaxf(acc[i][1] + bias.y, 0.f);
        o.z = fmaxf(acc[i][2] + bias.z, 0.f);
        o.w = fmaxf(acc[i][3] + bias.w, 0.f);
        *reinterpret_cast<float4*>(hout + node * D + col) = o;
    }
}

// ---------------------------------------------------------------------------
// out = h @ W_out + b_out     [N,128] @ [128,16] -> [N,16]
// ---------------------------------------------------------------------------
__global__ __launch_bounds__(256) void k_out(const float* __restrict__ h,
                                             const float* __restrict__ W,
                                             const float* __restrict__ b,
                                             float* __restrict__ out) {
    long t = (long)blockIdx.x * 256 + threadIdx.x;
    if (t >= (long)N_NODES * OUT_F) return;
    int n = (int)(t >> 4);
    int o = (int)t & 15;
    const float* hr = h + (long)n * D;
    float acc = b[o];
#pragma unroll
    for (int k = 0; k < D; k += 4) {
        float4 hv = *reinterpret_cast<const float4*>(hr + k);
        acc += hv.x * W[(k + 0) * OUT_F + o]
             + hv.y * W[(k + 1) * OUT_F + o]
             + hv.z * W[(k + 2) * OUT_F + o]
             + hv.w * W[(k + 3) * OUT_F + o];
    }
    out[t] = acc;
}

// ---------------------------------------------------------------------------
extern "C" void kernel_launch(void* const* d_in, const int* in_sizes, int n_in,
                              void* d_out, int out_size, void* d_ws, size_t ws_size,
                              hipStream_t stream) {
    const float* x      = (const float*)d_in[0];
    const int*   edge   = (const int*)d_in[1];
    const float* W_emb  = (const float*)d_in[2];
    const float* b_emb  = (const float*)d_in[3];
    const float* W1_rel = (const float*)d_in[4];
    const float* W1_root= (const float*)d_in[5];
    const float* b1     = (const float*)d_in[6];
    const float* W2_rel = (const float*)d_in[7];
    const float* W2_root= (const float*)d_in[8];
    const float* b2     = (const float*)d_in[9];
    const float* W_out  = (const float*)d_in[10];
    const float* b_out  = (const float*)d_in[11];
    float* out = (float*)d_out;

    const int* src = edge;
    const int* dst = edge + N_EDGES;

    // workspace layout (all 16B-aligned by construction)
    float* hA      = (float*)d_ws;                        // N*D
    float* hB      = hA + (size_t)N_NODES * D;            // N*D
    float* agg     = hB + (size_t)N_NODES * D;            // N*D
    int*   cnt     = (int*)(agg + (size_t)N_NODES * D);   // N
    int*   offsets = cnt + N_NODES;                       // N
    int*   cursor  = offsets + N_NODES;                   // N
    int*   bsums   = cursor + N_NODES;                    // NB
    int*   csr     = bsums + ((NB + 3) & ~3);             // E

    // ---- CSR build (int atomics only) ----
    hipMemsetAsync(cnt, 0, N_NODES * sizeof(int), stream);
    k_count<<<(N_EDGES + 255) / 256, 256, 0, stream>>>(dst, cnt);
    k_scan1<<<NB, 256, 0, stream>>>(cnt, offsets, bsums);
    k_scan2<<<1, 512, 0, stream>>>(bsums);
    k_scan3<<<NB, 256, 0, stream>>>(offsets, bsums, cursor);
    k_fill<<<(N_EDGES + 255) / 256, 256, 0, stream>>>(src, dst, cursor, csr);

    // ---- node embed ----
    k_embed<<<(N_NODES + 1) / 2, 256, 0, stream>>>(x, W_emb, b_emb, hA);

    // ---- conv1 ----
    k_gather<<<(N_NODES + 7) / 8, 256, 0, stream>>>(hA, csr, offsets, cnt, agg);
    k_transform<<<N_NODES / 32, 256, 0, stream>>>(agg, hA, W1_rel, W1_root, b1, hB);

    // ---- conv2 ----
    k_gather<<<(N_NODES + 7) / 8, 256, 0, stream>>>(hB, csr, offsets, cnt, agg);
    k_transform<<<N_NODES / 32, 256, 0, stream>>>(agg, hB, W2_rel, W2_root, b2, hA);

    // ---- final projection ----
    k_out<<<((long)N_NODES * OUT_F + 255) / 256, 256, 0, stream>>>(hA, W_out, b_out, out);
}

// Round 4
// 725.065 us; speedup vs baseline: 8.2279x; 1.2010x over previous
//
#include <hip/hip_runtime.h>
#include <hip/hip_bf16.h>

#define N_NODES 100000
#define N_EDGES 1600000
#define IN_F    32
#define D       128
#define OUT_F   16
#define NB      ((N_NODES + 255) / 256)   // 391 scan blocks

typedef __attribute__((ext_vector_type(8))) short  bf16x8;
typedef __attribute__((ext_vector_type(4))) float  f32x4;

__device__ __forceinline__ unsigned short f2bf(float x) {     // RNE f32 -> bf16 bits
    unsigned u = __float_as_uint(x);
    unsigned r = (u + 0x7FFFu + ((u >> 16) & 1u)) >> 16;
    return (unsigned short)r;
}
__device__ __forceinline__ float bf2f(unsigned short h) {
    return __uint_as_float(((unsigned)h) << 16);
}

// ---------------------------------------------------------------------------
// h0 = x @ W_emb + b_emb      [N,32] @ [32,128] -> [N,128]
// ---------------------------------------------------------------------------
__global__ __launch_bounds__(256) void k_embed(const float* __restrict__ x,
                                               const float* __restrict__ W,
                                               const float* __restrict__ b,
                                               float* __restrict__ h) {
    __shared__ float xs[2][IN_F];
    const int col = threadIdx.x & 127;
    const int ng  = threadIdx.x >> 7;
    const int node = blockIdx.x * 2 + ng;

    if (threadIdx.x < 64) {
        int r = threadIdx.x >> 5, c = threadIdx.x & 31;
        int n2 = blockIdx.x * 2 + r;
        xs[r][c] = (n2 < N_NODES) ? x[(long)n2 * IN_F + c] : 0.f;
    }
    __syncthreads();
    if (node >= N_NODES) return;

    float acc = b[col];
#pragma unroll
    for (int k = 0; k < IN_F; ++k)
        acc += xs[ng][k] * W[k * D + col];
    h[(long)node * D + col] = acc;
}

// ---------------------------------------------------------------------------
// in-degree counts
// ---------------------------------------------------------------------------
__global__ __launch_bounds__(256) void k_count(const int* __restrict__ dst,
                                               int* __restrict__ cnt) {
    int e = blockIdx.x * 256 + threadIdx.x;
    if (e < N_EDGES) atomicAdd(&cnt[dst[e]], 1);
}

// ---------------------------------------------------------------------------
// 3-kernel exclusive prefix scan of cnt[N_NODES] -> offsets (+ cursor copy)
// ---------------------------------------------------------------------------
__global__ __launch_bounds__(256) void k_scan1(const int* __restrict__ cnt,
                                               int* __restrict__ part,
                                               int* __restrict__ blockSums) {
    __shared__ int s[256];
    int i = blockIdx.x * 256 + threadIdx.x;
    int v = (i < N_NODES) ? cnt[i] : 0;
    s[threadIdx.x] = v;
    __syncthreads();
    for (int off = 1; off < 256; off <<= 1) {
        int x = (threadIdx.x >= off) ? s[threadIdx.x - off] : 0;
        __syncthreads();
        s[threadIdx.x] += x;
        __syncthreads();
    }
    if (i < N_NODES) part[i] = s[threadIdx.x] - v;
    if (threadIdx.x == 255) blockSums[blockIdx.x] = s[255];
}

__global__ __launch_bounds__(512) void k_scan2(int* __restrict__ blockSums) {
    __shared__ int s[512];
    int t = threadIdx.x;
    int v = (t < NB) ? blockSums[t] : 0;
    s[t] = v;
    __syncthreads();
    for (int off = 1; off < 512; off <<= 1) {
        int x = (t >= off) ? s[t - off] : 0;
        __syncthreads();
        s[t] += x;
        __syncthreads();
    }
    if (t < NB) blockSums[t] = s[t] - v;
}

__global__ __launch_bounds__(256) void k_scan3(int* __restrict__ offsets,
                                               const int* __restrict__ blockSums,
                                               int* __restrict__ cursor) {
    int i = blockIdx.x * 256 + threadIdx.x;
    if (i < N_NODES) {
        int o = offsets[i] + blockSums[blockIdx.x];
        offsets[i] = o;
        cursor[i]  = o;
    }
}

// ---------------------------------------------------------------------------
// fill CSR adjacency: csr[cursor[dst]++] = src
// ---------------------------------------------------------------------------
__global__ __launch_bounds__(256) void k_fill(const int* __restrict__ src,
                                              const int* __restrict__ dst,
                                              int* __restrict__ cursor,
                                              int* __restrict__ csr) {
    int e = blockIdx.x * 256 + threadIdx.x;
    if (e < N_EDGES) {
        int p = atomicAdd(&cursor[dst[e]], 1);
        csr[p] = src[e];
    }
}

// ---------------------------------------------------------------------------
// agg[n] = mean_{s in csr[n]} h[s]
// ---------------------------------------------------------------------------
__global__ __launch_bounds__(256) void k_gather(const float* __restrict__ h,
                                                const int* __restrict__ csr,
                                                const int* __restrict__ offsets,
                                                const int* __restrict__ cnt,
                                                float* __restrict__ agg) {
    const int node = blockIdx.x * 8 + (threadIdx.x >> 5);
    const int q = (threadIdx.x & 31) << 2;
    if (node >= N_NODES) return;

    const int beg = offsets[node];
    const int deg = cnt[node];
    const int end = beg + deg;

    float4 acc0 = make_float4(0.f, 0.f, 0.f, 0.f);
    float4 acc1 = make_float4(0.f, 0.f, 0.f, 0.f);
    int i = beg;
    for (; i + 3 < end; i += 4) {
        int s0 = csr[i], s1 = csr[i + 1], s2 = csr[i + 2], s3 = csr[i + 3];
        const float4 v0 = *reinterpret_cast<const float4*>(h + (long)s0 * D + q);
        const float4 v1 = *reinterpret_cast<const float4*>(h + (long)s1 * D + q);
        const float4 v2 = *reinterpret_cast<const float4*>(h + (long)s2 * D + q);
        const float4 v3 = *reinterpret_cast<const float4*>(h + (long)s3 * D + q);
        acc0.x += v0.x + v1.x;  acc1.x += v2.x + v3.x;
        acc0.y += v0.y + v1.y;  acc1.y += v2.y + v3.y;
        acc0.z += v0.z + v1.z;  acc1.z += v2.z + v3.z;
        acc0.w += v0.w + v1.w;  acc1.w += v2.w + v3.w;
    }
    for (; i < end; ++i) {
        int s0 = csr[i];
        const float4 v0 = *reinterpret_cast<const float4*>(h + (long)s0 * D + q);
        acc0.x += v0.x; acc0.y += v0.y; acc0.z += v0.z; acc0.w += v0.w;
    }
    acc0.x += acc1.x; acc0.y += acc1.y; acc0.z += acc1.z; acc0.w += acc1.w;

    const float sc = 1.f / fmaxf((float)deg, 1.f);
    acc0.x *= sc; acc0.y *= sc; acc0.z *= sc; acc0.w *= sc;
    *reinterpret_cast<float4*>(agg + (long)node * D + q) = acc0;
}

// ---------------------------------------------------------------------------
// Weight prep: split-bf16 pack of Wcat = [Wrel ; Wroot]  (256 x 128, f32)
// into B-fragment layout: pack[(ko*128 + n)*8 + j] = Wcat[ko*8+j][n]
// Layout per layer: hi at wp + layer*65536, lo at +32768.
// grid: 32 blocks x 256 threads; thread -> one (layer,ko,n) chunk of 8 k.
// ---------------------------------------------------------------------------
__global__ __launch_bounds__(256) void k_wprep(const float* __restrict__ W1r,
                                               const float* __restrict__ W1o,
                                               const float* __restrict__ W2r,
                                               const float* __restrict__ W2o,
                                               unsigned short* __restrict__ wp) {
    int c = blockIdx.x * 256 + threadIdx.x;        // 0..8191
    int layer = c >> 12;
    int ko = (c >> 7) & 31;
    int n = c & 127;
    const float* Wrel  = layer ? W2r : W1r;
    const float* Wroot = layer ? W2o : W1o;

    unsigned short hi[8], lo[8];
#pragma unroll
    for (int j = 0; j < 8; ++j) {
        int k = ko * 8 + j;
        float w = (k < D) ? Wrel[k * D + n] : Wroot[(k - D) * D + n];
        unsigned short h = f2bf(w);
        hi[j] = h;
        lo[j] = f2bf(w - bf2f(h));
    }
    unsigned short* base = wp + layer * 65536 + ((ko * 128 + n) << 3);
    *reinterpret_cast<bf16x8*>(base)         = *reinterpret_cast<bf16x8*>(hi);
    *reinterpret_cast<bf16x8*>(base + 32768) = *reinterpret_cast<bf16x8*>(lo);
}

// ---------------------------------------------------------------------------
// hout = relu( [agg|hin] (K=256) @ Wcat + b )  via split-bf16 MFMA.
// block: 256 threads = 4 waves, tile M=32 nodes x N=128 cols.
// wave (mw = wid&1, nw = wid>>1): rows mw*16..+15, cols nw*64..+63 (4 coltiles).
// A staged in LDS as hi/lo bf16, fragment layout Apack[ko][row][8], XOR-swizzled.
// 100000 % 32 == 0 -> no tail.
// MFMA 16x16x32_bf16: A: row=lane&15, k=8*(lane>>4)+j ; B: col=lane&15, same k;
// D: col=lane&15, row=4*(lane>>4)+reg  [verified m89].
// ---------------------------------------------------------------------------
__global__ __launch_bounds__(256) void k_transform(const float* __restrict__ agg,
                                                   const float* __restrict__ hin,
                                                   const unsigned short* __restrict__ Wh,
                                                   const unsigned short* __restrict__ Wl,
                                                   const float* __restrict__ b,
                                                   float* __restrict__ hout) {
    __shared__ unsigned short Ahi[32 * 32 * 8];   // 16 KB: [ko][row][8]
    __shared__ unsigned short Alo[32 * 32 * 8];   // 16 KB
    const int base = blockIdx.x * 32;

    // ---- stage + split: 32 rows x 256 k.  chunk c: ko = c&31 (lane-fastest
    // for coalesced global reads), row = c>>5.  LDS byte ^= (ko&7)<<4 so the
    // 512B-strided ds_writes spread across 16B slots (else 16-way conflict).
    for (int it = 0; it < 4; ++it) {
        int c  = it * 256 + threadIdx.x;          // 0..1023
        int ko = c & 31;
        int row = c >> 5;
        long node = base + row;
        const float* sp = (ko < 16) ? (agg + node * D + ko * 8)
                                    : (hin + node * D + (ko - 16) * 8);
        float4 v0 = *reinterpret_cast<const float4*>(sp);
        float4 v1 = *reinterpret_cast<const float4*>(sp + 4);
        float vv[8] = {v0.x, v0.y, v0.z, v0.w, v1.x, v1.y, v1.z, v1.w};
        unsigned short hh[8], ll[8];
#pragma unroll
        for (int j = 0; j < 8; ++j) {
            unsigned short h = f2bf(vv[j]);
            hh[j] = h;
            ll[j] = f2bf(vv[j] - bf2f(h));
        }
        int byteoff = ((ko * 32 + row) * 16) ^ ((ko & 7) << 4);
        *reinterpret_cast<bf16x8*>(reinterpret_cast<char*>(Ahi) + byteoff) =
            *reinterpret_cast<bf16x8*>(hh);
        *reinterpret_cast<bf16x8*>(reinterpret_cast<char*>(Alo) + byteoff) =
            *reinterpret_cast<bf16x8*>(ll);
    }
    __syncthreads();

    const int lane = threadIdx.x & 63;
    const int wid  = threadIdx.x >> 6;
    const int mw = wid & 1;                 // row strip 0/1
    const int nw = wid >> 1;                // col half 0/1
    const int l15 = lane & 15;
    const int l4  = lane >> 4;

    f32x4 acc[4];
#pragma unroll
    for (int ct = 0; ct < 4; ++ct) acc[ct] = (f32x4){0.f, 0.f, 0.f, 0.f};

    const int arow = mw * 16 + l15;

#pragma unroll
    for (int s = 0; s < 8; ++s) {
        const int ks = s * 4 + l4;
        const int abyte = ((ks * 32 + arow) * 16) ^ ((ks & 7) << 4);
        bf16x8 ah = *reinterpret_cast<const bf16x8*>(
                        reinterpret_cast<const char*>(Ahi) + abyte);
        bf16x8 al = *reinterpret_cast<const bf16x8*>(
                        reinterpret_cast<const char*>(Alo) + abyte);
#pragma unroll
        for (int ct = 0; ct < 4; ++ct) {
            const int colb = nw * 64 + ct * 16 + l15;
            const long bidx = ((long)(ks * 128 + colb)) << 3;
            bf16x8 bh = *reinterpret_cast<const bf16x8*>(Wh + bidx);
            bf16x8 bl = *reinterpret_cast<const bf16x8*>(Wl + bidx);
            acc[ct] = __builtin_amdgcn_mfma_f32_16x16x32_bf16(ah, bh, acc[ct], 0, 0, 0);
            acc[ct] = __builtin_amdgcn_mfma_f32_16x16x32_bf16(al, bh, acc[ct], 0, 0, 0);
            acc[ct] = __builtin_amdgcn_mfma_f32_16x16x32_bf16(ah, bl, acc[ct], 0, 0, 0);
        }
    }

    // epilogue: D col = lane&15, row = 4*(lane>>4)+r
#pragma unroll
    for (int ct = 0; ct < 4; ++ct) {
        const int col = nw * 64 + ct * 16 + l15;
        const float bv = b[col];
#pragma unroll
        for (int r = 0; r < 4; ++r) {
            long node = base + mw * 16 + l4 * 4 + r;
            hout[node * D + col] = fmaxf(acc[ct][r] + bv, 0.f);
        }
    }
}

// ---------------------------------------------------------------------------
// out = h @ W_out + b_out     [N,128] @ [128,16] -> [N,16]
// ---------------------------------------------------------------------------
__global__ __launch_bounds__(256) void k_out(const float* __restrict__ h,
                                             const float* __restrict__ W,
                                             const float* __restrict__ b,
                                             float* __restrict__ out) {
    long t = (long)blockIdx.x * 256 + threadIdx.x;
    if (t >= (long)N_NODES * OUT_F) return;
    int n = (int)(t >> 4);
    int o = (int)t & 15;
    const float* hr = h + (long)n * D;
    float acc = b[o];
#pragma unroll
    for (int k = 0; k < D; k += 4) {
        float4 hv = *reinterpret_cast<const float4*>(hr + k);
        acc += hv.x * W[(k + 0) * OUT_F + o]
             + hv.y * W[(k + 1) * OUT_F + o]
             + hv.z * W[(k + 2) * OUT_F + o]
             + hv.w * W[(k + 3) * OUT_F + o];
    }
    out[t] = acc;
}

// ---------------------------------------------------------------------------
extern "C" void kernel_launch(void* const* d_in, const int* in_sizes, int n_in,
                              void* d_out, int out_size, void* d_ws, size_t ws_size,
                              hipStream_t stream) {
    const float* x      = (const float*)d_in[0];
    const int*   edge   = (const int*)d_in[1];
    const float* W_emb  = (const float*)d_in[2];
    const float* b_emb  = (const float*)d_in[3];
    const float* W1_rel = (const float*)d_in[4];
    const float* W1_root= (const float*)d_in[5];
    const float* b1     = (const float*)d_in[6];
    const float* W2_rel = (const float*)d_in[7];
    const float* W2_root= (const float*)d_in[8];
    const float* b2     = (const float*)d_in[9];
    const float* W_out  = (const float*)d_in[10];
    const float* b_out  = (const float*)d_in[11];
    float* out = (float*)d_out;

    const int* src = edge;
    const int* dst = edge + N_EDGES;

    // workspace layout (16B-aligned by construction)
    float* hA      = (float*)d_ws;                        // N*D
    float* hB      = hA + (size_t)N_NODES * D;            // N*D
    float* agg     = hB + (size_t)N_NODES * D;            // N*D
    int*   cnt     = (int*)(agg + (size_t)N_NODES * D);   // N
    int*   offsets = cnt + N_NODES;                       // N
    int*   cursor  = offsets + N_NODES;                   // N
    int*   bsums   = cursor + N_NODES;                    // NB (pad to 400)
    unsigned short* wpack = (unsigned short*)(bsums + 400); // 4 x 32768 bf16
    int*   csr     = (int*)(wpack + 4 * 32768);           // E

    // ---- CSR build + weight prep ----
    hipMemsetAsync(cnt, 0, N_NODES * sizeof(int), stream);
    k_count<<<(N_EDGES + 255) / 256, 256, 0, stream>>>(dst, cnt);
    k_scan1<<<NB, 256, 0, stream>>>(cnt, offsets, bsums);
    k_scan2<<<1, 512, 0, stream>>>(bsums);
    k_scan3<<<NB, 256, 0, stream>>>(offsets, bsums, cursor);
    k_fill<<<(N_EDGES + 255) / 256, 256, 0, stream>>>(src, dst, cursor, csr);
    k_wprep<<<32, 256, 0, stream>>>(W1_rel, W1_root, W2_rel, W2_root, wpack);

    // ---- node embed ----
    k_embed<<<(N_NODES + 1) / 2, 256, 0, stream>>>(x, W_emb, b_emb, hA);

    // ---- conv1 ----
    k_gather<<<(N_NODES + 7) / 8, 256, 0, stream>>>(hA, csr, offsets, cnt, agg);
    k_transform<<<N_NODES / 32, 256, 0, stream>>>(agg, hA, wpack, wpack + 32768, b1, hB);

    // ---- conv2 ----
    k_gather<<<(N_NODES + 7) / 8, 256, 0, stream>>>(hB, csr, offsets, cnt, agg);
    k_transform<<<N_NODES / 32, 256, 0, stream>>>(agg, hB, wpack + 65536, wpack + 98304, b2, hA);

    // ---- final projection ----
    k_out<<<((long)N_NODES * OUT_F + 255) / 256, 256, 0, stream>>>(hA, W_out, b_out, out);
}

// Round 5
// 668.798 us; speedup vs baseline: 8.9201x; 1.0841x over previous
//
#include <hip/hip_runtime.h>
#include <hip/hip_bf16.h>

#define N_NODES 100000
#define N_EDGES 1600000
#define IN_F    32
#define D       128
#define OUT_F   16
#define NB      ((N_NODES + 255) / 256)   // 391 scan blocks
#define NSLICE  8
#define SLICE_NODES (N_NODES / NSLICE)    // 12500
#define FILL_CHUNKS 512                   // blocks per slice-group

typedef __attribute__((ext_vector_type(8))) short  bf16x8;
typedef __attribute__((ext_vector_type(4))) float  f32x4;

__device__ __forceinline__ unsigned short f2bf(float x) {     // RNE f32 -> bf16 bits
    unsigned u = __float_as_uint(x);
    unsigned r = (u + 0x7FFFu + ((u >> 16) & 1u)) >> 16;
    return (unsigned short)r;
}
__device__ __forceinline__ float bf2f(unsigned short h) {
    return __uint_as_float(((unsigned)h) << 16);
}

// ---------------------------------------------------------------------------
// h0 = x @ W_emb + b_emb      [N,32] @ [32,128] -> [N,128]
// ---------------------------------------------------------------------------
__global__ __launch_bounds__(256) void k_embed(const float* __restrict__ x,
                                               const float* __restrict__ W,
                                               const float* __restrict__ b,
                                               float* __restrict__ h) {
    __shared__ float xs[2][IN_F];
    const int col = threadIdx.x & 127;
    const int ng  = threadIdx.x >> 7;
    const int node = blockIdx.x * 2 + ng;

    if (threadIdx.x < 64) {
        int r = threadIdx.x >> 5, c = threadIdx.x & 31;
        int n2 = blockIdx.x * 2 + r;
        xs[r][c] = (n2 < N_NODES) ? x[(long)n2 * IN_F + c] : 0.f;
    }
    __syncthreads();
    if (node >= N_NODES) return;

    float acc = b[col];
#pragma unroll
    for (int k = 0; k < IN_F; ++k)
        acc += xs[ng][k] * W[k * D + col];
    h[(long)node * D + col] = acc;
}

// ---------------------------------------------------------------------------
// in-degree counts — slice-gated for XCD-local atomics/lines.
// grid: NSLICE * FILL_CHUNKS; slice = bid&7 (maps to one XCD round-robin).
// ---------------------------------------------------------------------------
__global__ __launch_bounds__(256) void k_count(const int* __restrict__ dst,
                                               int* __restrict__ cnt) {
    const int slice = blockIdx.x & (NSLICE - 1);
    const int chunk = blockIdx.x >> 3;
    const int lo = slice * SLICE_NODES;
    const int hi = lo + SLICE_NODES;
    for (int e = chunk * 256 + threadIdx.x; e < N_EDGES; e += FILL_CHUNKS * 256) {
        int d = dst[e];
        if (d >= lo && d < hi) atomicAdd(&cnt[d], 1);
    }
}

// ---------------------------------------------------------------------------
// 3-kernel exclusive prefix scan of cnt[N_NODES] -> offsets (+ cursor copy)
// ---------------------------------------------------------------------------
__global__ __launch_bounds__(256) void k_scan1(const int* __restrict__ cnt,
                                               int* __restrict__ part,
                                               int* __restrict__ blockSums) {
    __shared__ int s[256];
    int i = blockIdx.x * 256 + threadIdx.x;
    int v = (i < N_NODES) ? cnt[i] : 0;
    s[threadIdx.x] = v;
    __syncthreads();
    for (int off = 1; off < 256; off <<= 1) {
        int x = (threadIdx.x >= off) ? s[threadIdx.x - off] : 0;
        __syncthreads();
        s[threadIdx.x] += x;
        __syncthreads();
    }
    if (i < N_NODES) part[i] = s[threadIdx.x] - v;
    if (threadIdx.x == 255) blockSums[blockIdx.x] = s[255];
}

__global__ __launch_bounds__(512) void k_scan2(int* __restrict__ blockSums) {
    __shared__ int s[512];
    int t = threadIdx.x;
    int v = (t < NB) ? blockSums[t] : 0;
    s[t] = v;
    __syncthreads();
    for (int off = 1; off < 512; off <<= 1) {
        int x = (t >= off) ? s[t - off] : 0;
        __syncthreads();
        s[t] += x;
        __syncthreads();
    }
    if (t < NB) blockSums[t] = s[t] - v;
}

__global__ __launch_bounds__(256) void k_scan3(int* __restrict__ offsets,
                                               const int* __restrict__ blockSums,
                                               int* __restrict__ cursor) {
    int i = blockIdx.x * 256 + threadIdx.x;
    if (i < N_NODES) {
        int o = offsets[i] + blockSums[blockIdx.x];
        offsets[i] = o;
        cursor[i]  = o;
    }
}

// ---------------------------------------------------------------------------
// fill CSR adjacency: csr[cursor[dst]++] = src — slice-gated.
// Each slice-group (bid&7 -> one XCD) scans all edges, commits only its
// slice's: cursor slice = 50 KB, csr slice ~800 KB, both fit that XCD's L2
// -> full-line write combining instead of 4B/line evictions.
// dst/src re-reads (8x12.8 MB) are L3-resident.
// ---------------------------------------------------------------------------
__global__ __launch_bounds__(256) void k_fill(const int* __restrict__ src,
                                              const int* __restrict__ dst,
                                              int* __restrict__ cursor,
                                              int* __restrict__ csr) {
    const int slice = blockIdx.x & (NSLICE - 1);
    const int chunk = blockIdx.x >> 3;
    const int lo = slice * SLICE_NODES;
    const int hi = lo + SLICE_NODES;
    for (int e = chunk * 256 + threadIdx.x; e < N_EDGES; e += FILL_CHUNKS * 256) {
        int d = dst[e];
        if (d >= lo && d < hi) {
            int p = atomicAdd(&cursor[d], 1);
            csr[p] = src[e];
        }
    }
}

// ---------------------------------------------------------------------------
// agg[n] = mean_{s in csr[n]} h[s]
// ---------------------------------------------------------------------------
__global__ __launch_bounds__(256) void k_gather(const float* __restrict__ h,
                                                const int* __restrict__ csr,
                                                const int* __restrict__ offsets,
                                                const int* __restrict__ cnt,
                                                float* __restrict__ agg) {
    const int node = blockIdx.x * 8 + (threadIdx.x >> 5);
    const int q = (threadIdx.x & 31) << 2;
    if (node >= N_NODES) return;

    const int beg = offsets[node];
    const int deg = cnt[node];
    const int end = beg + deg;

    float4 acc0 = make_float4(0.f, 0.f, 0.f, 0.f);
    float4 acc1 = make_float4(0.f, 0.f, 0.f, 0.f);
    int i = beg;
    for (; i + 3 < end; i += 4) {
        int s0 = csr[i], s1 = csr[i + 1], s2 = csr[i + 2], s3 = csr[i + 3];
        const float4 v0 = *reinterpret_cast<const float4*>(h + (long)s0 * D + q);
        const float4 v1 = *reinterpret_cast<const float4*>(h + (long)s1 * D + q);
        const float4 v2 = *reinterpret_cast<const float4*>(h + (long)s2 * D + q);
        const float4 v3 = *reinterpret_cast<const float4*>(h + (long)s3 * D + q);
        acc0.x += v0.x + v1.x;  acc1.x += v2.x + v3.x;
        acc0.y += v0.y + v1.y;  acc1.y += v2.y + v3.y;
        acc0.z += v0.z + v1.z;  acc1.z += v2.z + v3.z;
        acc0.w += v0.w + v1.w;  acc1.w += v2.w + v3.w;
    }
    for (; i < end; ++i) {
        int s0 = csr[i];
        const float4 v0 = *reinterpret_cast<const float4*>(h + (long)s0 * D + q);
        acc0.x += v0.x; acc0.y += v0.y; acc0.z += v0.z; acc0.w += v0.w;
    }
    acc0.x += acc1.x; acc0.y += acc1.y; acc0.z += acc1.z; acc0.w += acc1.w;

    const float sc = 1.f / fmaxf((float)deg, 1.f);
    acc0.x *= sc; acc0.y *= sc; acc0.z *= sc; acc0.w *= sc;
    *reinterpret_cast<float4*>(agg + (long)node * D + q) = acc0;
}

// ---------------------------------------------------------------------------
// Weight prep: split-bf16 pack of Wcat = [Wrel ; Wroot]  (256 x 128, f32)
// into B-fragment layout: pack[(ko*128 + n)*8 + j] = Wcat[ko*8+j][n]
// ---------------------------------------------------------------------------
__global__ __launch_bounds__(256) void k_wprep(const float* __restrict__ W1r,
                                               const float* __restrict__ W1o,
                                               const float* __restrict__ W2r,
                                               const float* __restrict__ W2o,
                                               unsigned short* __restrict__ wp) {
    int c = blockIdx.x * 256 + threadIdx.x;        // 0..8191
    int layer = c >> 12;
    int ko = (c >> 7) & 31;
    int n = c & 127;
    const float* Wrel  = layer ? W2r : W1r;
    const float* Wroot = layer ? W2o : W1o;

    unsigned short hi[8], lo[8];
#pragma unroll
    for (int j = 0; j < 8; ++j) {
        int k = ko * 8 + j;
        float w = (k < D) ? Wrel[k * D + n] : Wroot[(k - D) * D + n];
        unsigned short h = f2bf(w);
        hi[j] = h;
        lo[j] = f2bf(w - bf2f(h));
    }
    unsigned short* base = wp + layer * 65536 + ((ko * 128 + n) << 3);
    *reinterpret_cast<bf16x8*>(base)         = *reinterpret_cast<bf16x8*>(hi);
    *reinterpret_cast<bf16x8*>(base + 32768) = *reinterpret_cast<bf16x8*>(lo);
}

// ---------------------------------------------------------------------------
// hout = relu( [agg|hin] (K=256) @ Wcat + b )  via split-bf16 MFMA.
// ---------------------------------------------------------------------------
__global__ __launch_bounds__(256) void k_transform(const float* __restrict__ agg,
                                                   const float* __restrict__ hin,
                                                   const unsigned short* __restrict__ Wh,
                                                   const unsigned short* __restrict__ Wl,
                                                   const float* __restrict__ b,
                                                   float* __restrict__ hout) {
    __shared__ unsigned short Ahi[32 * 32 * 8];   // 16 KB: [ko][row][8]
    __shared__ unsigned short Alo[32 * 32 * 8];   // 16 KB
    const int base = blockIdx.x * 32;

    for (int it = 0; it < 4; ++it) {
        int c  = it * 256 + threadIdx.x;          // 0..1023
        int ko = c & 31;
        int row = c >> 5;
        long node = base + row;
        const float* sp = (ko < 16) ? (agg + node * D + ko * 8)
                                    : (hin + node * D + (ko - 16) * 8);
        float4 v0 = *reinterpret_cast<const float4*>(sp);
        float4 v1 = *reinterpret_cast<const float4*>(sp + 4);
        float vv[8] = {v0.x, v0.y, v0.z, v0.w, v1.x, v1.y, v1.z, v1.w};
        unsigned short hh[8], ll[8];
#pragma unroll
        for (int j = 0; j < 8; ++j) {
            unsigned short h = f2bf(vv[j]);
            hh[j] = h;
            ll[j] = f2bf(vv[j] - bf2f(h));
        }
        int byteoff = ((ko * 32 + row) * 16) ^ ((ko & 7) << 4);
        *reinterpret_cast<bf16x8*>(reinterpret_cast<char*>(Ahi) + byteoff) =
            *reinterpret_cast<bf16x8*>(hh);
        *reinterpret_cast<bf16x8*>(reinterpret_cast<char*>(Alo) + byteoff) =
            *reinterpret_cast<bf16x8*>(ll);
    }
    __syncthreads();

    const int lane = threadIdx.x & 63;
    const int wid  = threadIdx.x >> 6;
    const int mw = wid & 1;
    const int nw = wid >> 1;
    const int l15 = lane & 15;
    const int l4  = lane >> 4;

    f32x4 acc[4];
#pragma unroll
    for (int ct = 0; ct < 4; ++ct) acc[ct] = (f32x4){0.f, 0.f, 0.f, 0.f};

    const int arow = mw * 16 + l15;

#pragma unroll
    for (int s = 0; s < 8; ++s) {
        const int ks = s * 4 + l4;
        const int abyte = ((ks * 32 + arow) * 16) ^ ((ks & 7) << 4);
        bf16x8 ah = *reinterpret_cast<const bf16x8*>(
                        reinterpret_cast<const char*>(Ahi) + abyte);
        bf16x8 al = *reinterpret_cast<const bf16x8*>(
                        reinterpret_cast<const char*>(Alo) + abyte);
#pragma unroll
        for (int ct = 0; ct < 4; ++ct) {
            const int colb = nw * 64 + ct * 16 + l15;
            const long bidx = ((long)(ks * 128 + colb)) << 3;
            bf16x8 bh = *reinterpret_cast<const bf16x8*>(Wh + bidx);
            bf16x8 bl = *reinterpret_cast<const bf16x8*>(Wl + bidx);
            acc[ct] = __builtin_amdgcn_mfma_f32_16x16x32_bf16(ah, bh, acc[ct], 0, 0, 0);
            acc[ct] = __builtin_amdgcn_mfma_f32_16x16x32_bf16(al, bh, acc[ct], 0, 0, 0);
            acc[ct] = __builtin_amdgcn_mfma_f32_16x16x32_bf16(ah, bl, acc[ct], 0, 0, 0);
        }
    }

#pragma unroll
    for (int ct = 0; ct < 4; ++ct) {
        const int col = nw * 64 + ct * 16 + l15;
        const float bv = b[col];
#pragma unroll
        for (int r = 0; r < 4; ++r) {
            long node = base + mw * 16 + l4 * 4 + r;
            hout[node * D + col] = fmaxf(acc[ct][r] + bv, 0.f);
        }
    }
}

// ---------------------------------------------------------------------------
// out = h @ W_out + b_out     [N,128] @ [128,16] -> [N,16]
// ---------------------------------------------------------------------------
__global__ __launch_bounds__(256) void k_out(const float* __restrict__ h,
                                             const float* __restrict__ W,
                                             const float* __restrict__ b,
                                             float* __restrict__ out) {
    long t = (long)blockIdx.x * 256 + threadIdx.x;
    if (t >= (long)N_NODES * OUT_F) return;
    int n = (int)(t >> 4);
    int o = (int)t & 15;
    const float* hr = h + (long)n * D;
    float acc = b[o];
#pragma unroll
    for (int k = 0; k < D; k += 4) {
        float4 hv = *reinterpret_cast<const float4*>(hr + k);
        acc += hv.x * W[(k + 0) * OUT_F + o]
             + hv.y * W[(k + 1) * OUT_F + o]
             + hv.z * W[(k + 2) * OUT_F + o]
             + hv.w * W[(k + 3) * OUT_F + o];
    }
    out[t] = acc;
}

// ---------------------------------------------------------------------------
extern "C" void kernel_launch(void* const* d_in, const int* in_sizes, int n_in,
                              void* d_out, int out_size, void* d_ws, size_t ws_size,
                              hipStream_t stream) {
    const float* x      = (const float*)d_in[0];
    const int*   edge   = (const int*)d_in[1];
    const float* W_emb  = (const float*)d_in[2];
    const float* b_emb  = (const float*)d_in[3];
    const float* W1_rel = (const float*)d_in[4];
    const float* W1_root= (const float*)d_in[5];
    const float* b1     = (const float*)d_in[6];
    const float* W2_rel = (const float*)d_in[7];
    const float* W2_root= (const float*)d_in[8];
    const float* b2     = (const float*)d_in[9];
    const float* W_out  = (const float*)d_in[10];
    const float* b_out  = (const float*)d_in[11];
    float* out = (float*)d_out;

    const int* src = edge;
    const int* dst = edge + N_EDGES;

    // workspace layout (16B-aligned by construction)
    float* hA      = (float*)d_ws;                        // N*D
    float* hB      = hA + (size_t)N_NODES * D;            // N*D
    float* agg     = hB + (size_t)N_NODES * D;            // N*D
    int*   cnt     = (int*)(agg + (size_t)N_NODES * D);   // N
    int*   offsets = cnt + N_NODES;                       // N
    int*   cursor  = offsets + N_NODES;                   // N
    int*   bsums   = cursor + N_NODES;                    // NB (pad to 400)
    unsigned short* wpack = (unsigned short*)(bsums + 400); // 4 x 32768 bf16
    int*   csr     = (int*)(wpack + 4 * 32768);           // E

    // ---- CSR build + weight prep ----
    hipMemsetAsync(cnt, 0, N_NODES * sizeof(int), stream);
    k_count<<<NSLICE * FILL_CHUNKS, 256, 0, stream>>>(dst, cnt);
    k_scan1<<<NB, 256, 0, stream>>>(cnt, offsets, bsums);
    k_scan2<<<1, 512, 0, stream>>>(bsums);
    k_scan3<<<NB, 256, 0, stream>>>(offsets, bsums, cursor);
    k_fill<<<NSLICE * FILL_CHUNKS, 256, 0, stream>>>(src, dst, cursor, csr);
    k_wprep<<<32, 256, 0, stream>>>(W1_rel, W1_root, W2_rel, W2_root, wpack);

    // ---- node embed ----
    k_embed<<<(N_NODES + 1) / 2, 256, 0, stream>>>(x, W_emb, b_emb, hA);

    // ---- conv1 ----
    k_gather<<<(N_NODES + 7) / 8, 256, 0, stream>>>(hA, csr, offsets, cnt, agg);
    k_transform<<<N_NODES / 32, 256, 0, stream>>>(agg, hA, wpack, wpack + 32768, b1, hB);

    // ---- conv2 ----
    k_gather<<<(N_NODES + 7) / 8, 256, 0, stream>>>(hB, csr, offsets, cnt, agg);
    k_transform<<<N_NODES / 32, 256, 0, stream>>>(agg, hB, wpack + 65536, wpack + 98304, b2, hA);

    // ---- final projection ----
    k_out<<<((long)N_NODES * OUT_F + 255) / 256, 256, 0, stream>>>(hA, W_out, b_out, out);
}

// Round 6
// 550.864 us; speedup vs baseline: 10.8298x; 1.2141x over previous
//
#include <hip/hip_runtime.h>
#include <hip/hip_bf16.h>

#define N_NODES 100000
#define N_EDGES 1600000
#define IN_F    32
#define D       128
#define OUT_F   16
#define NB      ((N_NODES + 255) / 256)   // 391 scan blocks
#define NSLICE  8
#define SLICE_NODES (N_NODES / NSLICE)    // 12500
#define FILL_CHUNKS 512                   // blocks per slice-group

typedef __attribute__((ext_vector_type(8))) short  bf16x8;
typedef __attribute__((ext_vector_type(4))) float  f32x4;

__device__ __forceinline__ unsigned short f2bf(float x) {     // RNE f32 -> bf16 bits
    unsigned u = __float_as_uint(x);
    unsigned r = (u + 0x7FFFu + ((u >> 16) & 1u)) >> 16;
    return (unsigned short)r;
}
__device__ __forceinline__ float bf2f(unsigned short h) {
    return __uint_as_float(((unsigned)h) << 16);
}

// ---------------------------------------------------------------------------
// h0 = x @ W_emb + b_emb  -> split bf16 pair (hi, lo)
// ---------------------------------------------------------------------------
__global__ __launch_bounds__(256) void k_embed(const float* __restrict__ x,
                                               const float* __restrict__ W,
                                               const float* __restrict__ b,
                                               unsigned short* __restrict__ h_hi,
                                               unsigned short* __restrict__ h_lo) {
    __shared__ float xs[2][IN_F];
    const int col = threadIdx.x & 127;
    const int ng  = threadIdx.x >> 7;
    const int node = blockIdx.x * 2 + ng;

    if (threadIdx.x < 64) {
        int r = threadIdx.x >> 5, c = threadIdx.x & 31;
        int n2 = blockIdx.x * 2 + r;
        xs[r][c] = (n2 < N_NODES) ? x[(long)n2 * IN_F + c] : 0.f;
    }
    __syncthreads();
    if (node >= N_NODES) return;

    float acc = b[col];
#pragma unroll
    for (int k = 0; k < IN_F; ++k)
        acc += xs[ng][k] * W[k * D + col];
    unsigned short hi = f2bf(acc);
    h_hi[(long)node * D + col] = hi;
    h_lo[(long)node * D + col] = f2bf(acc - bf2f(hi));
}

// ---------------------------------------------------------------------------
// in-degree counts — slice-gated for XCD-local atomics/lines.
// ---------------------------------------------------------------------------
__global__ __launch_bounds__(256) void k_count(const int* __restrict__ dst,
                                               int* __restrict__ cnt) {
    const int slice = blockIdx.x & (NSLICE - 1);
    const int chunk = blockIdx.x >> 3;
    const int lo = slice * SLICE_NODES;
    const int hi = lo + SLICE_NODES;
    for (int e = chunk * 256 + threadIdx.x; e < N_EDGES; e += FILL_CHUNKS * 256) {
        int d = dst[e];
        if (d >= lo && d < hi) atomicAdd(&cnt[d], 1);
    }
}

// ---------------------------------------------------------------------------
// 3-kernel exclusive prefix scan of cnt[N_NODES] -> offsets (+ cursor copy)
// ---------------------------------------------------------------------------
__global__ __launch_bounds__(256) void k_scan1(const int* __restrict__ cnt,
                                               int* __restrict__ part,
                                               int* __restrict__ blockSums) {
    __shared__ int s[256];
    int i = blockIdx.x * 256 + threadIdx.x;
    int v = (i < N_NODES) ? cnt[i] : 0;
    s[threadIdx.x] = v;
    __syncthreads();
    for (int off = 1; off < 256; off <<= 1) {
        int x = (threadIdx.x >= off) ? s[threadIdx.x - off] : 0;
        __syncthreads();
        s[threadIdx.x] += x;
        __syncthreads();
    }
    if (i < N_NODES) part[i] = s[threadIdx.x] - v;
    if (threadIdx.x == 255) blockSums[blockIdx.x] = s[255];
}

__global__ __launch_bounds__(512) void k_scan2(int* __restrict__ blockSums) {
    __shared__ int s[512];
    int t = threadIdx.x;
    int v = (t < NB) ? blockSums[t] : 0;
    s[t] = v;
    __syncthreads();
    for (int off = 1; off < 512; off <<= 1) {
        int x = (t >= off) ? s[t - off] : 0;
        __syncthreads();
        s[t] += x;
        __syncthreads();
    }
    if (t < NB) blockSums[t] = s[t] - v;
}

__global__ __launch_bounds__(256) void k_scan3(int* __restrict__ offsets,
                                               const int* __restrict__ blockSums,
                                               int* __restrict__ cursor) {
    int i = blockIdx.x * 256 + threadIdx.x;
    if (i < N_NODES) {
        int o = offsets[i] + blockSums[blockIdx.x];
        offsets[i] = o;
        cursor[i]  = o;
    }
}

// ---------------------------------------------------------------------------
// fill CSR adjacency: csr[cursor[dst]++] = src — slice-gated.
// ---------------------------------------------------------------------------
__global__ __launch_bounds__(256) void k_fill(const int* __restrict__ src,
                                              const int* __restrict__ dst,
                                              int* __restrict__ cursor,
                                              int* __restrict__ csr) {
    const int slice = blockIdx.x & (NSLICE - 1);
    const int chunk = blockIdx.x >> 3;
    const int lo = slice * SLICE_NODES;
    const int hi = lo + SLICE_NODES;
    for (int e = chunk * 256 + threadIdx.x; e < N_EDGES; e += FILL_CHUNKS * 256) {
        int d = dst[e];
        if (d >= lo && d < hi) {
            int p = atomicAdd(&cursor[d], 1);
            csr[p] = src[e];
        }
    }
}

// ---------------------------------------------------------------------------
// agg[n] = mean_{s in csr[n]} h_hi[s]   (bf16-hi gather: 256 B/edge random)
// block: 256 threads = 16 nodes x 16 lanes, bf16x8 (16 B) per lane.
// Output pre-split to (hi, lo) for the MFMA transform.
// N_NODES % 16 == 0 -> no tail.
// ---------------------------------------------------------------------------
__global__ __launch_bounds__(256) void k_gather(const unsigned short* __restrict__ h_hi,
                                                const int* __restrict__ csr,
                                                const int* __restrict__ offsets,
                                                const int* __restrict__ cnt,
                                                unsigned short* __restrict__ ag_hi,
                                                unsigned short* __restrict__ ag_lo) {
    const int node = blockIdx.x * 16 + (threadIdx.x >> 4);
    const int q8 = (threadIdx.x & 15) << 3;        // bf16 col offset (0,8,...,120)

    const int beg = offsets[node];
    const int deg = cnt[node];
    const int end = beg + deg;

    float a0[8], a1[8];
#pragma unroll
    for (int j = 0; j < 8; ++j) { a0[j] = 0.f; a1[j] = 0.f; }

    int i = beg;
    for (; i + 3 < end; i += 4) {
        int s0 = csr[i], s1 = csr[i + 1], s2 = csr[i + 2], s3 = csr[i + 3];
        bf16x8 v0 = *reinterpret_cast<const bf16x8*>(h_hi + (long)s0 * D + q8);
        bf16x8 v1 = *reinterpret_cast<const bf16x8*>(h_hi + (long)s1 * D + q8);
        bf16x8 v2 = *reinterpret_cast<const bf16x8*>(h_hi + (long)s2 * D + q8);
        bf16x8 v3 = *reinterpret_cast<const bf16x8*>(h_hi + (long)s3 * D + q8);
#pragma unroll
        for (int j = 0; j < 8; ++j) {
            a0[j] += bf2f((unsigned short)v0[j]) + bf2f((unsigned short)v1[j]);
            a1[j] += bf2f((unsigned short)v2[j]) + bf2f((unsigned short)v3[j]);
        }
    }
    for (; i < end; ++i) {
        int s0 = csr[i];
        bf16x8 v0 = *reinterpret_cast<const bf16x8*>(h_hi + (long)s0 * D + q8);
#pragma unroll
        for (int j = 0; j < 8; ++j) a0[j] += bf2f((unsigned short)v0[j]);
    }

    const float sc = 1.f / fmaxf((float)deg, 1.f);
    unsigned short hh[8], ll[8];
#pragma unroll
    for (int j = 0; j < 8; ++j) {
        float v = (a0[j] + a1[j]) * sc;
        unsigned short h = f2bf(v);
        hh[j] = h;
        ll[j] = f2bf(v - bf2f(h));
    }
    *reinterpret_cast<bf16x8*>(ag_hi + (long)node * D + q8) = *reinterpret_cast<bf16x8*>(hh);
    *reinterpret_cast<bf16x8*>(ag_lo + (long)node * D + q8) = *reinterpret_cast<bf16x8*>(ll);
}

// ---------------------------------------------------------------------------
// Weight prep: split-bf16 pack of Wcat = [Wrel ; Wroot]  (256 x 128, f32)
// into B-fragment layout: pack[(ko*128 + n)*8 + j] = Wcat[ko*8+j][n]
// ---------------------------------------------------------------------------
__global__ __launch_bounds__(256) void k_wprep(const float* __restrict__ W1r,
                                               const float* __restrict__ W1o,
                                               const float* __restrict__ W2r,
                                               const float* __restrict__ W2o,
                                               unsigned short* __restrict__ wp) {
    int c = blockIdx.x * 256 + threadIdx.x;        // 0..8191
    int layer = c >> 12;
    int ko = (c >> 7) & 31;
    int n = c & 127;
    const float* Wrel  = layer ? W2r : W1r;
    const float* Wroot = layer ? W2o : W1o;

    unsigned short hi[8], lo[8];
#pragma unroll
    for (int j = 0; j < 8; ++j) {
        int k = ko * 8 + j;
        float w = (k < D) ? Wrel[k * D + n] : Wroot[(k - D) * D + n];
        unsigned short h = f2bf(w);
        hi[j] = h;
        lo[j] = f2bf(w - bf2f(h));
    }
    unsigned short* base = wp + layer * 65536 + ((ko * 128 + n) << 3);
    *reinterpret_cast<bf16x8*>(base)         = *reinterpret_cast<bf16x8*>(hi);
    *reinterpret_cast<bf16x8*>(base + 32768) = *reinterpret_cast<bf16x8*>(lo);
}

// ---------------------------------------------------------------------------
// hout = relu( [agg|hin] (K=256) @ Wcat + b )  via split-bf16 MFMA.
// A operands arrive pre-split (hi/lo bf16 arrays) — staging is a pure copy.
// Output written pre-split for the next layer / k_out.
// ---------------------------------------------------------------------------
__global__ __launch_bounds__(256) void k_transform(const unsigned short* __restrict__ agg_hi,
                                                   const unsigned short* __restrict__ agg_lo,
                                                   const unsigned short* __restrict__ hin_hi,
                                                   const unsigned short* __restrict__ hin_lo,
                                                   const unsigned short* __restrict__ Wh,
                                                   const unsigned short* __restrict__ Wl,
                                                   const float* __restrict__ b,
                                                   unsigned short* __restrict__ ho_hi,
                                                   unsigned short* __restrict__ ho_lo) {
    __shared__ unsigned short Ahi[32 * 32 * 8];   // 16 KB: [ko][row][8]
    __shared__ unsigned short Alo[32 * 32 * 8];   // 16 KB
    const int base = blockIdx.x * 32;

    // stage: chunk c -> (ko = c&31, row = c>>5); LDS byte ^= (ko&7)<<4
    for (int it = 0; it < 4; ++it) {
        int c  = it * 256 + threadIdx.x;          // 0..1023
        int ko = c & 31;
        int row = c >> 5;
        long node = base + row;
        long off = (ko < 16) ? (node * D + ko * 8) : (node * D + (ko - 16) * 8);
        const unsigned short* ph = (ko < 16) ? agg_hi : hin_hi;
        const unsigned short* pl = (ko < 16) ? agg_lo : hin_lo;
        bf16x8 vh = *reinterpret_cast<const bf16x8*>(ph + off);
        bf16x8 vl = *reinterpret_cast<const bf16x8*>(pl + off);
        int byteoff = ((ko * 32 + row) * 16) ^ ((ko & 7) << 4);
        *reinterpret_cast<bf16x8*>(reinterpret_cast<char*>(Ahi) + byteoff) = vh;
        *reinterpret_cast<bf16x8*>(reinterpret_cast<char*>(Alo) + byteoff) = vl;
    }
    __syncthreads();

    const int lane = threadIdx.x & 63;
    const int wid  = threadIdx.x >> 6;
    const int mw = wid & 1;
    const int nw = wid >> 1;
    const int l15 = lane & 15;
    const int l4  = lane >> 4;

    f32x4 acc[4];
#pragma unroll
    for (int ct = 0; ct < 4; ++ct) acc[ct] = (f32x4){0.f, 0.f, 0.f, 0.f};

    const int arow = mw * 16 + l15;

#pragma unroll
    for (int s = 0; s < 8; ++s) {
        const int ks = s * 4 + l4;
        const int abyte = ((ks * 32 + arow) * 16) ^ ((ks & 7) << 4);
        bf16x8 ah = *reinterpret_cast<const bf16x8*>(
                        reinterpret_cast<const char*>(Ahi) + abyte);
        bf16x8 al = *reinterpret_cast<const bf16x8*>(
                        reinterpret_cast<const char*>(Alo) + abyte);
#pragma unroll
        for (int ct = 0; ct < 4; ++ct) {
            const int colb = nw * 64 + ct * 16 + l15;
            const long bidx = ((long)(ks * 128 + colb)) << 3;
            bf16x8 bh = *reinterpret_cast<const bf16x8*>(Wh + bidx);
            bf16x8 bl = *reinterpret_cast<const bf16x8*>(Wl + bidx);
            acc[ct] = __builtin_amdgcn_mfma_f32_16x16x32_bf16(ah, bh, acc[ct], 0, 0, 0);
            acc[ct] = __builtin_amdgcn_mfma_f32_16x16x32_bf16(al, bh, acc[ct], 0, 0, 0);
            acc[ct] = __builtin_amdgcn_mfma_f32_16x16x32_bf16(ah, bl, acc[ct], 0, 0, 0);
        }
    }

    // epilogue: D col = lane&15, row = 4*(lane>>4)+r ; split-write
#pragma unroll
    for (int ct = 0; ct < 4; ++ct) {
        const int col = nw * 64 + ct * 16 + l15;
        const float bv = b[col];
#pragma unroll
        for (int r = 0; r < 4; ++r) {
            long node = base + mw * 16 + l4 * 4 + r;
            float v = fmaxf(acc[ct][r] + bv, 0.f);
            unsigned short h = f2bf(v);
            ho_hi[node * D + col] = h;
            ho_lo[node * D + col] = f2bf(v - bf2f(h));
        }
    }
}

// ---------------------------------------------------------------------------
// out = h @ W_out + b_out     [N,128] @ [128,16] -> [N,16]
// h reconstructed from (hi, lo) bf16 pair.
// ---------------------------------------------------------------------------
__global__ __launch_bounds__(256) void k_out(const unsigned short* __restrict__ h_hi,
                                             const unsigned short* __restrict__ h_lo,
                                             const float* __restrict__ W,
                                             const float* __restrict__ b,
                                             float* __restrict__ out) {
    long t = (long)blockIdx.x * 256 + threadIdx.x;
    if (t >= (long)N_NODES * OUT_F) return;
    int n = (int)(t >> 4);
    int o = (int)t & 15;
    const unsigned short* hh = h_hi + (long)n * D;
    const unsigned short* hl = h_lo + (long)n * D;
    float acc = b[o];
#pragma unroll
    for (int k = 0; k < D; k += 8) {
        bf16x8 vh = *reinterpret_cast<const bf16x8*>(hh + k);
        bf16x8 vl = *reinterpret_cast<const bf16x8*>(hl + k);
#pragma unroll
        for (int j = 0; j < 8; ++j) {
            float v = bf2f((unsigned short)vh[j]) + bf2f((unsigned short)vl[j]);
            acc += v * W[(k + j) * OUT_F + o];
        }
    }
    out[t] = acc;
}

// ---------------------------------------------------------------------------
extern "C" void kernel_launch(void* const* d_in, const int* in_sizes, int n_in,
                              void* d_out, int out_size, void* d_ws, size_t ws_size,
                              hipStream_t stream) {
    const float* x      = (const float*)d_in[0];
    const int*   edge   = (const int*)d_in[1];
    const float* W_emb  = (const float*)d_in[2];
    const float* b_emb  = (const float*)d_in[3];
    const float* W1_rel = (const float*)d_in[4];
    const float* W1_root= (const float*)d_in[5];
    const float* b1     = (const float*)d_in[6];
    const float* W2_rel = (const float*)d_in[7];
    const float* W2_root= (const float*)d_in[8];
    const float* b2     = (const float*)d_in[9];
    const float* W_out  = (const float*)d_in[10];
    const float* b_out  = (const float*)d_in[11];
    float* out = (float*)d_out;

    const int* src = edge;
    const int* dst = edge + N_EDGES;

    const size_t ND = (size_t)N_NODES * D;

    // workspace layout (16B-aligned: ND*2 bytes = 25.6 MB, multiple of 16)
    unsigned short* hA_hi = (unsigned short*)d_ws;        // ND bf16
    unsigned short* hA_lo = hA_hi + ND;
    unsigned short* hB_hi = hA_lo + ND;
    unsigned short* hB_lo = hB_hi + ND;
    unsigned short* ag_hi = hB_lo + ND;
    unsigned short* ag_lo = ag_hi + ND;
    int*   cnt     = (int*)(ag_lo + ND);                  // N
    int*   offsets = cnt + N_NODES;                       // N
    int*   cursor  = offsets + N_NODES;                   // N
    int*   bsums   = cursor + N_NODES;                    // NB (pad to 400)
    unsigned short* wpack = (unsigned short*)(bsums + 400); // 4 x 32768 bf16
    int*   csr     = (int*)(wpack + 4 * 32768);           // E

    // ---- CSR build + weight prep ----
    hipMemsetAsync(cnt, 0, N_NODES * sizeof(int), stream);
    k_count<<<NSLICE * FILL_CHUNKS, 256, 0, stream>>>(dst, cnt);
    k_scan1<<<NB, 256, 0, stream>>>(cnt, offsets, bsums);
    k_scan2<<<1, 512, 0, stream>>>(bsums);
    k_scan3<<<NB, 256, 0, stream>>>(offsets, bsums, cursor);
    k_fill<<<NSLICE * FILL_CHUNKS, 256, 0, stream>>>(src, dst, cursor, csr);
    k_wprep<<<32, 256, 0, stream>>>(W1_rel, W1_root, W2_rel, W2_root, wpack);

    // ---- node embed ----
    k_embed<<<(N_NODES + 1) / 2, 256, 0, stream>>>(x, W_emb, b_emb, hA_hi, hA_lo);

    // ---- conv1 ----
    k_gather<<<N_NODES / 16, 256, 0, stream>>>(hA_hi, csr, offsets, cnt, ag_hi, ag_lo);
    k_transform<<<N_NODES / 32, 256, 0, stream>>>(ag_hi, ag_lo, hA_hi, hA_lo,
                                                  wpack, wpack + 32768, b1, hB_hi, hB_lo);

    // ---- conv2 ----
    k_gather<<<N_NODES / 16, 256, 0, stream>>>(hB_hi, csr, offsets, cnt, ag_hi, ag_lo);
    k_transform<<<N_NODES / 32, 256, 0, stream>>>(ag_hi, ag_lo, hB_hi, hB_lo,
                                                  wpack + 65536, wpack + 98304, b2, hA_hi, hA_lo);

    // ---- final projection ----
    k_out<<<((long)N_NODES * OUT_F + 255) / 256, 256, 0, stream>>>(hA_hi, hA_lo, W_out, b_out, out);
}

// Round 7
// 505.007 us; speedup vs baseline: 11.8132x; 1.0908x over previous
//
#include <hip/hip_runtime.h>
#include <hip/hip_bf16.h>

#define N_NODES 100000
#define N_EDGES 1600000
#define IN_F    32
#define D       128
#define OUT_F   16
#define NB      ((N_NODES + 255) / 256)   // 391 scan blocks
#define NSLICE  8
#define SLICE_NODES (N_NODES / NSLICE)    // 12500
#define FILL_CHUNKS 512                   // blocks per slice-group

typedef __attribute__((ext_vector_type(8))) short  bf16x8;
typedef __attribute__((ext_vector_type(4))) float  f32x4;

__device__ __forceinline__ unsigned short f2bf(float x) {     // RNE f32 -> bf16 bits
    unsigned u = __float_as_uint(x);
    unsigned r = (u + 0x7FFFu + ((u >> 16) & 1u)) >> 16;
    return (unsigned short)r;
}
__device__ __forceinline__ float bf2f(unsigned short h) {
    return __uint_as_float(((unsigned)h) << 16);
}

// ---------------------------------------------------------------------------
// h0 = x @ W_emb + b_emb  -> split bf16 pair (hi, lo)
// 16 nodes/block, 256 threads = 16 nodes x 16 lanes x 8 cols.
// ---------------------------------------------------------------------------
__global__ __launch_bounds__(256) void k_embed(const float* __restrict__ x,
                                               const float* __restrict__ W,
                                               const float* __restrict__ b,
                                               unsigned short* __restrict__ h_hi,
                                               unsigned short* __restrict__ h_lo) {
    __shared__ float xs[16][IN_F];
    const int base = blockIdx.x * 16;

    if (threadIdx.x < 128) {
        int r = threadIdx.x >> 3, c4 = (threadIdx.x & 7) << 2;
        *reinterpret_cast<float4*>(&xs[r][c4]) =
            *reinterpret_cast<const float4*>(x + (long)(base + r) * IN_F + c4);
    }
    __syncthreads();

    const int nl   = threadIdx.x >> 4;          // node 0..15
    const int col0 = (threadIdx.x & 15) << 3;   // cols col0..col0+7

    float acc[8];
    {
        float4 b0 = *reinterpret_cast<const float4*>(b + col0);
        float4 b1 = *reinterpret_cast<const float4*>(b + col0 + 4);
        acc[0] = b0.x; acc[1] = b0.y; acc[2] = b0.z; acc[3] = b0.w;
        acc[4] = b1.x; acc[5] = b1.y; acc[6] = b1.z; acc[7] = b1.w;
    }
#pragma unroll
    for (int k = 0; k < IN_F; ++k) {
        const float xv = xs[nl][k];
        float4 w0 = *reinterpret_cast<const float4*>(W + k * D + col0);
        float4 w1 = *reinterpret_cast<const float4*>(W + k * D + col0 + 4);
        acc[0] += xv * w0.x; acc[1] += xv * w0.y; acc[2] += xv * w0.z; acc[3] += xv * w0.w;
        acc[4] += xv * w1.x; acc[5] += xv * w1.y; acc[6] += xv * w1.z; acc[7] += xv * w1.w;
    }

    unsigned short hh[8], ll[8];
#pragma unroll
    for (int j = 0; j < 8; ++j) {
        unsigned short h = f2bf(acc[j]);
        hh[j] = h;
        ll[j] = f2bf(acc[j] - bf2f(h));
    }
    long off = (long)(base + nl) * D + col0;
    *reinterpret_cast<bf16x8*>(h_hi + off) = *reinterpret_cast<bf16x8*>(hh);
    *reinterpret_cast<bf16x8*>(h_lo + off) = *reinterpret_cast<bf16x8*>(ll);
}

// ---------------------------------------------------------------------------
// in-degree counts — slice-gated for XCD-local atomics/lines.
// ---------------------------------------------------------------------------
__global__ __launch_bounds__(256) void k_count(const int* __restrict__ dst,
                                               int* __restrict__ cnt) {
    const int slice = blockIdx.x & (NSLICE - 1);
    const int chunk = blockIdx.x >> 3;
    const int lo = slice * SLICE_NODES;
    const int hi = lo + SLICE_NODES;
    for (int e = chunk * 256 + threadIdx.x; e < N_EDGES; e += FILL_CHUNKS * 256) {
        int d = dst[e];
        if (d >= lo && d < hi) atomicAdd(&cnt[d], 1);
    }
}

// ---------------------------------------------------------------------------
// 3-kernel exclusive prefix scan of cnt[N_NODES] -> offsets (+ cursor copy)
// ---------------------------------------------------------------------------
__global__ __launch_bounds__(256) void k_scan1(const int* __restrict__ cnt,
                                               int* __restrict__ part,
                                               int* __restrict__ blockSums) {
    __shared__ int s[256];
    int i = blockIdx.x * 256 + threadIdx.x;
    int v = (i < N_NODES) ? cnt[i] : 0;
    s[threadIdx.x] = v;
    __syncthreads();
    for (int off = 1; off < 256; off <<= 1) {
        int x = (threadIdx.x >= off) ? s[threadIdx.x - off] : 0;
        __syncthreads();
        s[threadIdx.x] += x;
        __syncthreads();
    }
    if (i < N_NODES) part[i] = s[threadIdx.x] - v;
    if (threadIdx.x == 255) blockSums[blockIdx.x] = s[255];
}

__global__ __launch_bounds__(512) void k_scan2(int* __restrict__ blockSums) {
    __shared__ int s[512];
    int t = threadIdx.x;
    int v = (t < NB) ? blockSums[t] : 0;
    s[t] = v;
    __syncthreads();
    for (int off = 1; off < 512; off <<= 1) {
        int x = (t >= off) ? s[t - off] : 0;
        __syncthreads();
        s[t] += x;
        __syncthreads();
    }
    if (t < NB) blockSums[t] = s[t] - v;
}

__global__ __launch_bounds__(256) void k_scan3(int* __restrict__ offsets,
                                               const int* __restrict__ blockSums,
                                               int* __restrict__ cursor) {
    int i = blockIdx.x * 256 + threadIdx.x;
    if (i < N_NODES) {
        int o = offsets[i] + blockSums[blockIdx.x];
        offsets[i] = o;
        cursor[i]  = o;
    }
}

// ---------------------------------------------------------------------------
// fill CSR adjacency: csr[cursor[dst]++] = src — slice-gated.
// ---------------------------------------------------------------------------
__global__ __launch_bounds__(256) void k_fill(const int* __restrict__ src,
                                              const int* __restrict__ dst,
                                              int* __restrict__ cursor,
                                              int* __restrict__ csr) {
    const int slice = blockIdx.x & (NSLICE - 1);
    const int chunk = blockIdx.x >> 3;
    const int lo = slice * SLICE_NODES;
    const int hi = lo + SLICE_NODES;
    for (int e = chunk * 256 + threadIdx.x; e < N_EDGES; e += FILL_CHUNKS * 256) {
        int d = dst[e];
        if (d >= lo && d < hi) {
            int p = atomicAdd(&cursor[d], 1);
            csr[p] = src[e];
        }
    }
}

// ---------------------------------------------------------------------------
// Weight prep: split-bf16 pack of Wcat = [Wrel ; Wroot]  (256 x 128, f32)
// into B-fragment layout: pack[(ko*128 + n)*8 + j] = Wcat[ko*8+j][n]
// ---------------------------------------------------------------------------
__global__ __launch_bounds__(256) void k_wprep(const float* __restrict__ W1r,
                                               const float* __restrict__ W1o,
                                               const float* __restrict__ W2r,
                                               const float* __restrict__ W2o,
                                               unsigned short* __restrict__ wp) {
    int c = blockIdx.x * 256 + threadIdx.x;        // 0..8191
    int layer = c >> 12;
    int ko = (c >> 7) & 31;
    int n = c & 127;
    const float* Wrel  = layer ? W2r : W1r;
    const float* Wroot = layer ? W2o : W1o;

    unsigned short hi[8], lo[8];
#pragma unroll
    for (int j = 0; j < 8; ++j) {
        int k = ko * 8 + j;
        float w = (k < D) ? Wrel[k * D + n] : Wroot[(k - D) * D + n];
        unsigned short h = f2bf(w);
        hi[j] = h;
        lo[j] = f2bf(w - bf2f(h));
    }
    unsigned short* base = wp + layer * 65536 + ((ko * 128 + n) << 3);
    *reinterpret_cast<bf16x8*>(base)         = *reinterpret_cast<bf16x8*>(hi);
    *reinterpret_cast<bf16x8*>(base + 32768) = *reinterpret_cast<bf16x8*>(lo);
}

// ---------------------------------------------------------------------------
// Fused RGCN layer: gather-mean -> split-bf16 MFMA transform (-> out proj).
// Block = 32 nodes, 256 threads, LDS A-tile [ko 0..31][row 0..31] hi/lo.
//   gather phase: ko 0..15 (mean of neighbors' h_hi, split on the fly)
//   stage  phase: ko 16..31 (root hin hi/lo copy)
//   MFMA: K=256 split-bf16, 3 products (hh, lh, hl)
//   LAST=0: relu + split-write hout(hi/lo)
//   LAST=1: relu -> f32 h in LDS (bank-rotated) -> out = h @ W_out + b_out
// ---------------------------------------------------------------------------
template <bool LAST>
__global__ __launch_bounds__(256) void k_fused(const unsigned short* __restrict__ hin_hi,
                                               const unsigned short* __restrict__ hin_lo,
                                               const int* __restrict__ csr,
                                               const int* __restrict__ offsets,
                                               const int* __restrict__ cnt,
                                               const unsigned short* __restrict__ Wh,
                                               const unsigned short* __restrict__ Wl,
                                               const float* __restrict__ b,
                                               unsigned short* __restrict__ ho_hi,
                                               unsigned short* __restrict__ ho_lo,
                                               const float* __restrict__ Wout,
                                               const float* __restrict__ bout,
                                               float* __restrict__ outp) {
    __shared__ unsigned short Ahi[32 * 32 * 8];   // 16 KB: [ko][row][8] swizzled
    __shared__ unsigned short Alo[32 * 32 * 8];   // 16 KB
    const int base = blockIdx.x * 32;
    const int tid  = threadIdx.x;

    // ---- gather phase: agg section ko = 0..15 ----
    {
        const int ko = tid & 15;
        const int q8 = ko << 3;
        for (int half = 0; half < 2; ++half) {
            const int row  = half * 16 + (tid >> 4);
            const int node = base + row;
            const int beg = offsets[node];
            const int deg = cnt[node];
            const int end = beg + deg;

            float a0[8], a1[8];
#pragma unroll
            for (int j = 0; j < 8; ++j) { a0[j] = 0.f; a1[j] = 0.f; }

            int i = beg;
            for (; i + 3 < end; i += 4) {
                int s0 = csr[i], s1 = csr[i + 1], s2 = csr[i + 2], s3 = csr[i + 3];
                bf16x8 v0 = *reinterpret_cast<const bf16x8*>(hin_hi + (long)s0 * D + q8);
                bf16x8 v1 = *reinterpret_cast<const bf16x8*>(hin_hi + (long)s1 * D + q8);
                bf16x8 v2 = *reinterpret_cast<const bf16x8*>(hin_hi + (long)s2 * D + q8);
                bf16x8 v3 = *reinterpret_cast<const bf16x8*>(hin_hi + (long)s3 * D + q8);
#pragma unroll
                for (int j = 0; j < 8; ++j) {
                    a0[j] += bf2f((unsigned short)v0[j]) + bf2f((unsigned short)v1[j]);
                    a1[j] += bf2f((unsigned short)v2[j]) + bf2f((unsigned short)v3[j]);
                }
            }
            for (; i < end; ++i) {
                int s0 = csr[i];
                bf16x8 v0 = *reinterpret_cast<const bf16x8*>(hin_hi + (long)s0 * D + q8);
#pragma unroll
                for (int j = 0; j < 8; ++j) a0[j] += bf2f((unsigned short)v0[j]);
            }

            const float sc = 1.f / fmaxf((float)deg, 1.f);
            unsigned short hh[8], ll[8];
#pragma unroll
            for (int j = 0; j < 8; ++j) {
                float v = (a0[j] + a1[j]) * sc;
                unsigned short h = f2bf(v);
                hh[j] = h;
                ll[j] = f2bf(v - bf2f(h));
            }
            const int byteoff = ((ko * 32 + row) * 16) ^ ((ko & 7) << 4);
            *reinterpret_cast<bf16x8*>(reinterpret_cast<char*>(Ahi) + byteoff) =
                *reinterpret_cast<bf16x8*>(hh);
            *reinterpret_cast<bf16x8*>(reinterpret_cast<char*>(Alo) + byteoff) =
                *reinterpret_cast<bf16x8*>(ll);
        }
    }

    // ---- stage root rows: ko = 16..31 (pure copy, pre-split input) ----
    for (int it = 0; it < 2; ++it) {
        int c = it * 256 + tid;            // 0..511
        int ko16 = c & 15;
        int row  = c >> 4;
        long off = (long)(base + row) * D + ko16 * 8;
        bf16x8 vh = *reinterpret_cast<const bf16x8*>(hin_hi + off);
        bf16x8 vl = *reinterpret_cast<const bf16x8*>(hin_lo + off);
        int ko = 16 + ko16;
        int byteoff = ((ko * 32 + row) * 16) ^ ((ko & 7) << 4);
        *reinterpret_cast<bf16x8*>(reinterpret_cast<char*>(Ahi) + byteoff) = vh;
        *reinterpret_cast<bf16x8*>(reinterpret_cast<char*>(Alo) + byteoff) = vl;
    }
    __syncthreads();

    // ---- MFMA: wave quadrant (mw rows, nw col-half) ----
    const int lane = tid & 63;
    const int wid  = tid >> 6;
    const int mw = wid & 1;
    const int nw = wid >> 1;
    const int l15 = lane & 15;
    const int l4  = lane >> 4;

    f32x4 acc[4];
#pragma unroll
    for (int ct = 0; ct < 4; ++ct) acc[ct] = (f32x4){0.f, 0.f, 0.f, 0.f};

    const int arow = mw * 16 + l15;

#pragma unroll
    for (int s = 0; s < 8; ++s) {
        const int ks = s * 4 + l4;
        const int abyte = ((ks * 32 + arow) * 16) ^ ((ks & 7) << 4);
        bf16x8 ah = *reinterpret_cast<const bf16x8*>(
                        reinterpret_cast<const char*>(Ahi) + abyte);
        bf16x8 al = *reinterpret_cast<const bf16x8*>(
                        reinterpret_cast<const char*>(Alo) + abyte);
#pragma unroll
        for (int ct = 0; ct < 4; ++ct) {
            const int colb = nw * 64 + ct * 16 + l15;
            const long bidx = ((long)(ks * 128 + colb)) << 3;
            bf16x8 bh = *reinterpret_cast<const bf16x8*>(Wh + bidx);
            bf16x8 bl = *reinterpret_cast<const bf16x8*>(Wl + bidx);
            acc[ct] = __builtin_amdgcn_mfma_f32_16x16x32_bf16(ah, bh, acc[ct], 0, 0, 0);
            acc[ct] = __builtin_amdgcn_mfma_f32_16x16x32_bf16(al, bh, acc[ct], 0, 0, 0);
            acc[ct] = __builtin_amdgcn_mfma_f32_16x16x32_bf16(ah, bl, acc[ct], 0, 0, 0);
        }
    }

    if (!LAST) {
        // relu + split-write to global hout
#pragma unroll
        for (int ct = 0; ct < 4; ++ct) {
            const int col = nw * 64 + ct * 16 + l15;
            const float bv = b[col];
#pragma unroll
            for (int r = 0; r < 4; ++r) {
                long node = base + mw * 16 + l4 * 4 + r;
                float v = fmaxf(acc[ct][r] + bv, 0.f);
                unsigned short h = f2bf(v);
                ho_hi[node * D + col] = h;
                ho_lo[node * D + col] = f2bf(v - bf2f(h));
            }
        }
    } else {
        // relu -> f32 h in LDS (bank-rotated by 4*node) -> projection to OUT
        __syncthreads();                       // all MFMA LDS reads complete
        float* hsm = reinterpret_cast<float*>(Ahi);   // 32 x 128 f32 = 16 KB
#pragma unroll
        for (int ct = 0; ct < 4; ++ct) {
            const int col = nw * 64 + ct * 16 + l15;
            const float bv = b[col];
#pragma unroll
            for (int r = 0; r < 4; ++r) {
                int nl = mw * 16 + l4 * 4 + r;
                hsm[nl * D + ((col + 4 * nl) & 127)] = fmaxf(acc[ct][r] + bv, 0.f);
            }
        }
        __syncthreads();

        const int nl = tid >> 3;               // node 0..31
        const int oo = (tid & 7) << 1;         // out cols oo, oo+1
        float acc0 = bout[oo];
        float acc1 = bout[oo + 1];
#pragma unroll 8
        for (int k = 0; k < D; ++k) {
            float hv = hsm[nl * D + ((k + 4 * nl) & 127)];
            float2 w = *reinterpret_cast<const float2*>(Wout + k * OUT_F + oo);
            acc0 += hv * w.x;
            acc1 += hv * w.y;
        }
        float2 o2 = make_float2(acc0, acc1);
        *reinterpret_cast<float2*>(outp + (long)(base + nl) * OUT_F + oo) = o2;
    }
}

// ---------------------------------------------------------------------------
extern "C" void kernel_launch(void* const* d_in, const int* in_sizes, int n_in,
                              void* d_out, int out_size, void* d_ws, size_t ws_size,
                              hipStream_t stream) {
    const float* x      = (const float*)d_in[0];
    const int*   edge   = (const int*)d_in[1];
    const float* W_emb  = (const float*)d_in[2];
    const float* b_emb  = (const float*)d_in[3];
    const float* W1_rel = (const float*)d_in[4];
    const float* W1_root= (const float*)d_in[5];
    const float* b1     = (const float*)d_in[6];
    const float* W2_rel = (const float*)d_in[7];
    const float* W2_root= (const float*)d_in[8];
    const float* b2     = (const float*)d_in[9];
    const float* W_out  = (const float*)d_in[10];
    const float* b_out  = (const float*)d_in[11];
    float* out = (float*)d_out;

    const int* src = edge;
    const int* dst = edge + N_EDGES;

    const size_t ND = (size_t)N_NODES * D;

    // workspace layout (16B-aligned by construction)
    unsigned short* hA_hi = (unsigned short*)d_ws;        // ND bf16
    unsigned short* hA_lo = hA_hi + ND;
    unsigned short* hB_hi = hA_lo + ND;
    unsigned short* hB_lo = hB_hi + ND;
    int*   cnt     = (int*)(hB_lo + ND);                  // N
    int*   offsets = cnt + N_NODES;                       // N
    int*   cursor  = offsets + N_NODES;                   // N
    int*   bsums   = cursor + N_NODES;                    // NB (pad to 400)
    unsigned short* wpack = (unsigned short*)(bsums + 400); // 4 x 32768 bf16
    int*   csr     = (int*)(wpack + 4 * 32768);           // E

    // ---- CSR build + weight prep ----
    hipMemsetAsync(cnt, 0, N_NODES * sizeof(int), stream);
    k_count<<<NSLICE * FILL_CHUNKS, 256, 0, stream>>>(dst, cnt);
    k_scan1<<<NB, 256, 0, stream>>>(cnt, offsets, bsums);
    k_scan2<<<1, 512, 0, stream>>>(bsums);
    k_scan3<<<NB, 256, 0, stream>>>(offsets, bsums, cursor);
    k_fill<<<NSLICE * FILL_CHUNKS, 256, 0, stream>>>(src, dst, cursor, csr);
    k_wprep<<<32, 256, 0, stream>>>(W1_rel, W1_root, W2_rel, W2_root, wpack);

    // ---- node embed ----
    k_embed<<<N_NODES / 16, 256, 0, stream>>>(x, W_emb, b_emb, hA_hi, hA_lo);

    // ---- conv1 (fused gather + transform) ----
    k_fused<false><<<N_NODES / 32, 256, 0, stream>>>(
        hA_hi, hA_lo, csr, offsets, cnt,
        wpack, wpack + 32768, b1, hB_hi, hB_lo, nullptr, nullptr, nullptr);

    // ---- conv2 + output projection (fused) ----
    k_fused<true><<<N_NODES / 32, 256, 0, stream>>>(
        hB_hi, hB_lo, csr, offsets, cnt,
        wpack + 65536, wpack + 98304, b2, nullptr, nullptr, W_out, b_out, out);
}

// Round 9
// 460.929 us; speedup vs baseline: 12.9429x; 1.0956x over previous
//
#include <hip/hip_runtime.h>
#include <hip/hip_bf16.h>

#define N_NODES 100000
#define N_EDGES 1600000
#define IN_F    32
#define D       128
#define OUT_F   16
#define NB      ((N_NODES + 255) / 256)   // 391 scan blocks
#define NSLICE  8
#define SLICE_NODES (N_NODES / NSLICE)    // 12500
#define FILL_CHUNKS 512                   // blocks per slice-group

typedef __attribute__((ext_vector_type(8))) short  bf16x8;
typedef __attribute__((ext_vector_type(4))) float  f32x4;

__device__ __forceinline__ unsigned short f2bf(float x) {     // RNE f32 -> bf16 bits
    unsigned u = __float_as_uint(x);
    unsigned r = (u + 0x7FFFu + ((u >> 16) & 1u)) >> 16;
    return (unsigned short)r;
}
__device__ __forceinline__ float bf2f(unsigned short h) {
    return __uint_as_float(((unsigned)h) << 16);
}

// ---------------------------------------------------------------------------
// h0 = x @ W_emb + b_emb  -> split bf16 pair (hi, lo)
// 16 nodes/block, 256 threads = 16 nodes x 16 lanes x 8 cols.
// ---------------------------------------------------------------------------
__global__ __launch_bounds__(256) void k_embed(const float* __restrict__ x,
                                               const float* __restrict__ W,
                                               const float* __restrict__ b,
                                               unsigned short* __restrict__ h_hi,
                                               unsigned short* __restrict__ h_lo) {
    __shared__ float xs[16][IN_F];
    const int base = blockIdx.x * 16;

    if (threadIdx.x < 128) {
        int r = threadIdx.x >> 3, c4 = (threadIdx.x & 7) << 2;
        *reinterpret_cast<float4*>(&xs[r][c4]) =
            *reinterpret_cast<const float4*>(x + (long)(base + r) * IN_F + c4);
    }
    __syncthreads();

    const int nl   = threadIdx.x >> 4;          // node 0..15
    const int col0 = (threadIdx.x & 15) << 3;   // cols col0..col0+7

    float acc[8];
    {
        float4 b0 = *reinterpret_cast<const float4*>(b + col0);
        float4 b1 = *reinterpret_cast<const float4*>(b + col0 + 4);
        acc[0] = b0.x; acc[1] = b0.y; acc[2] = b0.z; acc[3] = b0.w;
        acc[4] = b1.x; acc[5] = b1.y; acc[6] = b1.z; acc[7] = b1.w;
    }
#pragma unroll
    for (int k = 0; k < IN_F; ++k) {
        const float xv = xs[nl][k];
        float4 w0 = *reinterpret_cast<const float4*>(W + k * D + col0);
        float4 w1 = *reinterpret_cast<const float4*>(W + k * D + col0 + 4);
        acc[0] += xv * w0.x; acc[1] += xv * w0.y; acc[2] += xv * w0.z; acc[3] += xv * w0.w;
        acc[4] += xv * w1.x; acc[5] += xv * w1.y; acc[6] += xv * w1.z; acc[7] += xv * w1.w;
    }

    unsigned short hh[8], ll[8];
#pragma unroll
    for (int j = 0; j < 8; ++j) {
        unsigned short h = f2bf(acc[j]);
        hh[j] = h;
        ll[j] = f2bf(acc[j] - bf2f(h));
    }
    long off = (long)(base + nl) * D + col0;
    *reinterpret_cast<bf16x8*>(h_hi + off) = *reinterpret_cast<bf16x8*>(hh);
    *reinterpret_cast<bf16x8*>(h_lo + off) = *reinterpret_cast<bf16x8*>(ll);
}

// ---------------------------------------------------------------------------
// in-degree counts — slice-gated for XCD-local atomics/lines.
// ---------------------------------------------------------------------------
__global__ __launch_bounds__(256) void k_count(const int* __restrict__ dst,
                                               int* __restrict__ cnt) {
    const int slice = blockIdx.x & (NSLICE - 1);
    const int chunk = blockIdx.x >> 3;
    const int lo = slice * SLICE_NODES;
    const int hi = lo + SLICE_NODES;
    for (int e = chunk * 256 + threadIdx.x; e < N_EDGES; e += FILL_CHUNKS * 256) {
        int d = dst[e];
        if (d >= lo && d < hi) atomicAdd(&cnt[d], 1);
    }
}

// ---------------------------------------------------------------------------
// 3-kernel exclusive prefix scan of cnt[N_NODES] -> offsets (+ cursor copy)
// ---------------------------------------------------------------------------
__global__ __launch_bounds__(256) void k_scan1(const int* __restrict__ cnt,
                                               int* __restrict__ part,
                                               int* __restrict__ blockSums) {
    __shared__ int s[256];
    int i = blockIdx.x * 256 + threadIdx.x;
    int v = (i < N_NODES) ? cnt[i] : 0;
    s[threadIdx.x] = v;
    __syncthreads();
    for (int off = 1; off < 256; off <<= 1) {
        int x = (threadIdx.x >= off) ? s[threadIdx.x - off] : 0;
        __syncthreads();
        s[threadIdx.x] += x;
        __syncthreads();
    }
    if (i < N_NODES) part[i] = s[threadIdx.x] - v;
    if (threadIdx.x == 255) blockSums[blockIdx.x] = s[255];
}

__global__ __launch_bounds__(512) void k_scan2(int* __restrict__ blockSums) {
    __shared__ int s[512];
    int t = threadIdx.x;
    int v = (t < NB) ? blockSums[t] : 0;
    s[t] = v;
    __syncthreads();
    for (int off = 1; off < 512; off <<= 1) {
        int x = (t >= off) ? s[t - off] : 0;
        __syncthreads();
        s[t] += x;
        __syncthreads();
    }
    if (t < NB) blockSums[t] = s[t] - v;
}

__global__ __launch_bounds__(256) void k_scan3(int* __restrict__ offsets,
                                               const int* __restrict__ blockSums,
                                               int* __restrict__ cursor) {
    int i = blockIdx.x * 256 + threadIdx.x;
    if (i < N_NODES) {
        int o = offsets[i] + blockSums[blockIdx.x];
        offsets[i] = o;
        cursor[i]  = o;
    }
}

// ---------------------------------------------------------------------------
// fill CSR adjacency: csr[cursor[dst]++] = src — slice-gated.
// ---------------------------------------------------------------------------
__global__ __launch_bounds__(256) void k_fill(const int* __restrict__ src,
                                              const int* __restrict__ dst,
                                              int* __restrict__ cursor,
                                              int* __restrict__ csr) {
    const int slice = blockIdx.x & (NSLICE - 1);
    const int chunk = blockIdx.x >> 3;
    const int lo = slice * SLICE_NODES;
    const int hi = lo + SLICE_NODES;
    for (int e = chunk * 256 + threadIdx.x; e < N_EDGES; e += FILL_CHUNKS * 256) {
        int d = dst[e];
        if (d >= lo && d < hi) {
            int p = atomicAdd(&cursor[d], 1);
            csr[p] = src[e];
        }
    }
}

// ---------------------------------------------------------------------------
// Weight prep: split-bf16 pack of Wcat = [Wrel ; Wroot]  (256 x 128, f32)
// into B-fragment layout: pack[(ko*128 + n)*8 + j] = Wcat[ko*8+j][n]
// ---------------------------------------------------------------------------
__global__ __launch_bounds__(256) void k_wprep(const float* __restrict__ W1r,
                                               const float* __restrict__ W1o,
                                               const float* __restrict__ W2r,
                                               const float* __restrict__ W2o,
                                               unsigned short* __restrict__ wp) {
    int c = blockIdx.x * 256 + threadIdx.x;        // 0..8191
    int layer = c >> 12;
    int ko = (c >> 7) & 31;
    int n = c & 127;
    const float* Wrel  = layer ? W2r : W1r;
    const float* Wroot = layer ? W2o : W1o;

    unsigned short hi[8], lo[8];
#pragma unroll
    for (int j = 0; j < 8; ++j) {
        int k = ko * 8 + j;
        float w = (k < D) ? Wrel[k * D + n] : Wroot[(k - D) * D + n];
        unsigned short h = f2bf(w);
        hi[j] = h;
        lo[j] = f2bf(w - bf2f(h));
    }
    unsigned short* base = wp + layer * 65536 + ((ko * 128 + n) << 3);
    *reinterpret_cast<bf16x8*>(base)         = *reinterpret_cast<bf16x8*>(hi);
    *reinterpret_cast<bf16x8*>(base + 32768) = *reinterpret_cast<bf16x8*>(lo);
}

// ---------------------------------------------------------------------------
// Fused RGCN layer, 512 threads / 32 nodes.
//   gather: one (node, col-chunk) per thread (32x16 = 512) — round-6 shape,
//           full memory-level parallelism; mean split to swizzled LDS ko 0..15
//   stage : ko 16..31 root copy (512 threads, 1 chunk each)
//   MFMA  : 8 waves; wave (mw=wid&1, nwq=wid>>1) does rows mw*16..+15,
//           cols nwq*32..+31 (2 coltiles), K=256 split-bf16 (hh, lh, hl)
//   LAST=0: relu + split-write hout(hi/lo)
//   LAST=1: relu -> f32 h in LDS (bank-rotated) -> out = h @ W_out + b_out
// ---------------------------------------------------------------------------
template <bool LAST>
__global__ __launch_bounds__(512) void k_fused(const unsigned short* __restrict__ hin_hi,
                                               const unsigned short* __restrict__ hin_lo,
                                               const int* __restrict__ csr,
                                               const int* __restrict__ offsets,
                                               const int* __restrict__ cnt,
                                               const unsigned short* __restrict__ Wh,
                                               const unsigned short* __restrict__ Wl,
                                               const float* __restrict__ b,
                                               unsigned short* __restrict__ ho_hi,
                                               unsigned short* __restrict__ ho_lo,
                                               const float* __restrict__ Wout,
                                               const float* __restrict__ bout,
                                               float* __restrict__ outp) {
    __shared__ unsigned short Ahi[32 * 32 * 8];   // 16 KB: [ko][row][8] swizzled
    __shared__ unsigned short Alo[32 * 32 * 8];   // 16 KB
    const int base = blockIdx.x * 32;
    const int tid  = threadIdx.x;

    // ---- gather phase: ko = 0..15, one (node,chunk) per thread ----
    {
        const int ko  = tid & 15;
        const int q8  = ko << 3;
        const int row = tid >> 4;                 // 0..31
        const int node = base + row;
        const int beg = offsets[node];
        const int deg = cnt[node];
        const int end = beg + deg;

        float a0[8], a1[8];
#pragma unroll
        for (int j = 0; j < 8; ++j) { a0[j] = 0.f; a1[j] = 0.f; }

        int i = beg;
        for (; i + 3 < end; i += 4) {
            int s0 = csr[i], s1 = csr[i + 1], s2 = csr[i + 2], s3 = csr[i + 3];
            bf16x8 v0 = *reinterpret_cast<const bf16x8*>(hin_hi + (long)s0 * D + q8);
            bf16x8 v1 = *reinterpret_cast<const bf16x8*>(hin_hi + (long)s1 * D + q8);
            bf16x8 v2 = *reinterpret_cast<const bf16x8*>(hin_hi + (long)s2 * D + q8);
            bf16x8 v3 = *reinterpret_cast<const bf16x8*>(hin_hi + (long)s3 * D + q8);
#pragma unroll
            for (int j = 0; j < 8; ++j) {
                a0[j] += bf2f((unsigned short)v0[j]) + bf2f((unsigned short)v1[j]);
                a1[j] += bf2f((unsigned short)v2[j]) + bf2f((unsigned short)v3[j]);
            }
        }
        for (; i < end; ++i) {
            int s0 = csr[i];
            bf16x8 v0 = *reinterpret_cast<const bf16x8*>(hin_hi + (long)s0 * D + q8);
#pragma unroll
            for (int j = 0; j < 8; ++j) a0[j] += bf2f((unsigned short)v0[j]);
        }

        const float sc = 1.f / fmaxf((float)deg, 1.f);
        unsigned short hh[8], ll[8];
#pragma unroll
        for (int j = 0; j < 8; ++j) {
            float v = (a0[j] + a1[j]) * sc;
            unsigned short h = f2bf(v);
            hh[j] = h;
            ll[j] = f2bf(v - bf2f(h));
        }
        const int byteoff = ((ko * 32 + row) * 16) ^ ((ko & 7) << 4);
        *reinterpret_cast<bf16x8*>(reinterpret_cast<char*>(Ahi) + byteoff) =
            *reinterpret_cast<bf16x8*>(hh);
        *reinterpret_cast<bf16x8*>(reinterpret_cast<char*>(Alo) + byteoff) =
            *reinterpret_cast<bf16x8*>(ll);
    }

    // ---- stage root rows: ko = 16..31 (pure copy, pre-split input) ----
    {
        int ko16 = tid & 15;
        int row  = tid >> 4;
        long off = (long)(base + row) * D + ko16 * 8;
        bf16x8 vh = *reinterpret_cast<const bf16x8*>(hin_hi + off);
        bf16x8 vl = *reinterpret_cast<const bf16x8*>(hin_lo + off);
        int ko = 16 + ko16;
        int byteoff = ((ko * 32 + row) * 16) ^ ((ko & 7) << 4);
        *reinterpret_cast<bf16x8*>(reinterpret_cast<char*>(Ahi) + byteoff) = vh;
        *reinterpret_cast<bf16x8*>(reinterpret_cast<char*>(Alo) + byteoff) = vl;
    }
    __syncthreads();

    // ---- MFMA: 8 waves, wave = (mw rows, nwq col-quarter) ----
    const int lane = tid & 63;
    const int wid  = tid >> 6;          // 0..7
    const int mw  = wid & 1;
    const int nwq = wid >> 1;           // 0..3
    const int l15 = lane & 15;
    const int l4  = lane >> 4;

    f32x4 acc[2];
#pragma unroll
    for (int ct = 0; ct < 2; ++ct) acc[ct] = (f32x4){0.f, 0.f, 0.f, 0.f};

    const int arow = mw * 16 + l15;

#pragma unroll
    for (int s = 0; s < 8; ++s) {
        const int ks = s * 4 + l4;
        const int abyte = ((ks * 32 + arow) * 16) ^ ((ks & 7) << 4);
        bf16x8 ah = *reinterpret_cast<const bf16x8*>(
                        reinterpret_cast<const char*>(Ahi) + abyte);
        bf16x8 al = *reinterpret_cast<const bf16x8*>(
                        reinterpret_cast<const char*>(Alo) + abyte);
#pragma unroll
        for (int ct = 0; ct < 2; ++ct) {
            const int colb = nwq * 32 + ct * 16 + l15;
            const long bidx = ((long)(ks * 128 + colb)) << 3;
            bf16x8 bh = *reinterpret_cast<const bf16x8*>(Wh + bidx);
            bf16x8 bl = *reinterpret_cast<const bf16x8*>(Wl + bidx);
            acc[ct] = __builtin_amdgcn_mfma_f32_16x16x32_bf16(ah, bh, acc[ct], 0, 0, 0);
            acc[ct] = __builtin_amdgcn_mfma_f32_16x16x32_bf16(al, bh, acc[ct], 0, 0, 0);
            acc[ct] = __builtin_amdgcn_mfma_f32_16x16x32_bf16(ah, bl, acc[ct], 0, 0, 0);
        }
    }

    if (!LAST) {
        // relu + split-write to global hout
#pragma unroll
        for (int ct = 0; ct < 2; ++ct) {
            const int col = nwq * 32 + ct * 16 + l15;
            const float bv = b[col];
#pragma unroll
            for (int r = 0; r < 4; ++r) {
                long node = base + mw * 16 + l4 * 4 + r;
                float v = fmaxf(acc[ct][r] + bv, 0.f);
                unsigned short h = f2bf(v);
                ho_hi[node * D + col] = h;
                ho_lo[node * D + col] = f2bf(v - bf2f(h));
            }
        }
    } else {
        // relu -> f32 h in LDS (bank-rotated by 4*node) -> projection to OUT
        __syncthreads();                       // all MFMA LDS reads complete
        float* hsm = reinterpret_cast<float*>(Ahi);   // 32 x 128 f32 = 16 KB
#pragma unroll
        for (int ct = 0; ct < 2; ++ct) {
            const int col = nwq * 32 + ct * 16 + l15;
            const float bv = b[col];
#pragma unroll
            for (int r = 0; r < 4; ++r) {
                int nl = mw * 16 + l4 * 4 + r;
                hsm[nl * D + ((col + 4 * nl) & 127)] = fmaxf(acc[ct][r] + bv, 0.f);
            }
        }
        __syncthreads();

        const int nl = tid >> 4;               // node 0..31
        const int oo = tid & 15;               // out col 0..15
        float acc0 = bout[oo];
#pragma unroll 8
        for (int k = 0; k < D; ++k) {
            float hv = hsm[nl * D + ((k + 4 * nl) & 127)];
            acc0 += hv * Wout[k * OUT_F + oo];
        }
        outp[(long)(base + nl) * OUT_F + oo] = acc0;
    }
}

// ---------------------------------------------------------------------------
extern "C" void kernel_launch(void* const* d_in, const int* in_sizes, int n_in,
                              void* d_out, int out_size, void* d_ws, size_t ws_size,
                              hipStream_t stream) {
    const float* x      = (const float*)d_in[0];
    const int*   edge   = (const int*)d_in[1];
    const float* W_emb  = (const float*)d_in[2];
    const float* b_emb  = (const float*)d_in[3];
    const float* W1_rel = (const float*)d_in[4];
    const float* W1_root= (const float*)d_in[5];
    const float* b1     = (const float*)d_in[6];
    const float* W2_rel = (const float*)d_in[7];
    const float* W2_root= (const float*)d_in[8];
    const float* b2     = (const float*)d_in[9];
    const float* W_out  = (const float*)d_in[10];
    const float* b_out  = (const float*)d_in[11];
    float* out = (float*)d_out;

    const int* src = edge;
    const int* dst = edge + N_EDGES;

    const size_t ND = (size_t)N_NODES * D;

    // workspace layout (16B-aligned by construction)
    unsigned short* hA_hi = (unsigned short*)d_ws;        // ND bf16
    unsigned short* hA_lo = hA_hi + ND;
    unsigned short* hB_hi = hA_lo + ND;
    unsigned short* hB_lo = hB_hi + ND;
    int*   cnt     = (int*)(hB_lo + ND);                  // N
    int*   offsets = cnt + N_NODES;                       // N
    int*   cursor  = offsets + N_NODES;                   // N
    int*   bsums   = cursor + N_NODES;                    // NB (pad to 400)
    unsigned short* wpack = (unsigned short*)(bsums + 400); // 4 x 32768 bf16
    int*   csr     = (int*)(wpack + 4 * 32768);           // E

    // ---- CSR build + weight prep ----
    hipMemsetAsync(cnt, 0, N_NODES * sizeof(int), stream);
    k_count<<<NSLICE * FILL_CHUNKS, 256, 0, stream>>>(dst, cnt);
    k_scan1<<<NB, 256, 0, stream>>>(cnt, offsets, bsums);
    k_scan2<<<1, 512, 0, stream>>>(bsums);
    k_scan3<<<NB, 256, 0, stream>>>(offsets, bsums, cursor);
    k_fill<<<NSLICE * FILL_CHUNKS, 256, 0, stream>>>(src, dst, cursor, csr);
    k_wprep<<<32, 256, 0, stream>>>(W1_rel, W1_root, W2_rel, W2_root, wpack);

    // ---- node embed ----
    k_embed<<<N_NODES / 16, 256, 0, stream>>>(x, W_emb, b_emb, hA_hi, hA_lo);

    // ---- conv1 (fused gather + transform) ----
    k_fused<false><<<N_NODES / 32, 512, 0, stream>>>(
        hA_hi, hA_lo, csr, offsets, cnt,
        wpack, wpack + 32768, b1, hB_hi, hB_lo, nullptr, nullptr, nullptr);

    // ---- conv2 + output projection (fused) ----
    k_fused<true><<<N_NODES / 32, 512, 0, stream>>>(
        hB_hi, hB_lo, csr, offsets, cnt,
        wpack + 65536, wpack + 98304, b2, nullptr, nullptr, W_out, b_out, out);
}